// Round 1
// baseline (1040.623 us; speedup 1.0000x reference)
//
#include <hip/hip_runtime.h>
#include <hip/hip_bf16.h>

// ---------------------------------------------------------------------------
// GCN pipeline:
//  deg -> dinv -> GEMM1 -> agg1 -> bias/relu(+selfloop) -> GEMM2 -> agg2
//      -> bias/relu(+selfloop) -> mean-pool -> MLP head
// H = F = 64 (== wave width). fp32 throughout.
// ---------------------------------------------------------------------------

// deg[row[e]] += attr[e]   (self-loop "+1" folded into k_dinv)
__global__ __launch_bounds__(256) void k_deg(const int* __restrict__ rows,
                                             const float* __restrict__ attr,
                                             float* __restrict__ deg, int E) {
    int e = blockIdx.x * 256 + threadIdx.x;
    if (e < E) atomicAdd(&deg[rows[e]], attr[e]);
}

// dinv[i] = rsqrt(deg[i] + 1)   (deg >= 1 always, no zero guard needed)
__global__ __launch_bounds__(256) void k_dinv(float* __restrict__ deg, int n) {
    int i = blockIdx.x * 256 + threadIdx.x;
    if (i < n) deg[i] = rsqrtf(deg[i] + 1.0f);
}

// out[n x 64] = in[n x 64] @ W[64 x 64]   (no bias)
// block = 256 threads = 4 rows x 64 cols; W staged in LDS.
__global__ __launch_bounds__(256) void k_gemm64(const float* __restrict__ in,
                                                const float* __restrict__ W,
                                                float* __restrict__ out, int n) {
    __shared__ float ws[64 * 64];
    __shared__ float xs[4 * 64];
    int tid = threadIdx.x;
    for (int i = tid; i < 64 * 64; i += 256) ws[i] = W[i];
    int lr  = tid >> 6;      // 0..3 local row
    int col = tid & 63;      // 0..63
    int row = blockIdx.x * 4 + lr;
    if (row < n) xs[lr * 64 + col] = in[row * 64 + col];
    __syncthreads();
    if (row < n) {
        float acc = 0.0f;
#pragma unroll
        for (int k = 0; k < 64; ++k) acc += xs[lr * 64 + k] * ws[k * 64 + col];
        out[row * 64 + col] = acc;
    }
}

// One wave per edge, one lane per feature:
//   out[row, lane] += dinv[row]*attr*dinv[col] * src[col, lane]
__global__ __launch_bounds__(256) void k_agg(const float* __restrict__ src,
                                             const int* __restrict__ rows,
                                             const int* __restrict__ cols,
                                             const float* __restrict__ attr,
                                             const float* __restrict__ dinv,
                                             float* __restrict__ out, int E) {
    int e    = blockIdx.x * 4 + (threadIdx.x >> 6);
    int lane = threadIdx.x & 63;
    if (e < E) {
        int r = rows[e];
        int c = cols[e];
        float nrm = dinv[r] * attr[e] * dinv[c];
        atomicAdd(&out[r * 64 + lane], nrm * src[c * 64 + lane]);
    }
}

// h[i,j] = relu(agg[i,j] + dinv[i]^2 * xw[i,j] + b[j])   (in place on agg)
__global__ __launch_bounds__(256) void k_post(float* __restrict__ agg,
                                              const float* __restrict__ xw,
                                              const float* __restrict__ dinv,
                                              const float* __restrict__ b, int n) {
    int idx = blockIdx.x * 256 + threadIdx.x;
    if (idx < n * 64) {
        int i = idx >> 6, j = idx & 63;
        float d = dinv[i];
        float v = agg[idx] + d * d * xw[idx] + b[j];
        agg[idx] = v > 0.0f ? v : 0.0f;
    }
}

// pool[j] += sum_i h[i,j]
__global__ __launch_bounds__(256) void k_pool(const float* __restrict__ h,
                                              float* __restrict__ pool, int n) {
    __shared__ float part[4][64];
    int lr = threadIdx.x >> 6, col = threadIdx.x & 63;
    float acc = 0.0f;
    for (int i = blockIdx.x * 4 + lr; i < n; i += gridDim.x * 4)
        acc += h[i * 64 + col];
    part[lr][col] = acc;
    __syncthreads();
    if (lr == 0) {
        float s = part[0][col] + part[1][col] + part[2][col] + part[3][col];
        atomicAdd(&pool[col], s);
    }
}

// z = [pool/N, h_other]; out = relu(z @ Wc1 + bc1) @ Wc2 + bc2
__global__ __launch_bounds__(128) void k_head(const float* __restrict__ pool,
                                              const float* __restrict__ h_other,
                                              const float* __restrict__ Wc1,
                                              const float* __restrict__ bc1,
                                              const float* __restrict__ Wc2,
                                              const float* __restrict__ bc2,
                                              float* __restrict__ out, float invN) {
    __shared__ float z[128];
    __shared__ float hid[64];
    int t = threadIdx.x;  // 128 threads
    z[t] = (t < 64) ? pool[t] * invN : h_other[t - 64];
    __syncthreads();
    if (t < 64) {
        float acc = bc1[t];
#pragma unroll
        for (int k = 0; k < 128; ++k) acc += z[k] * Wc1[k * 64 + t];
        hid[t] = acc > 0.0f ? acc : 0.0f;
    }
    __syncthreads();
    if (t < 3) {
        float acc = bc2[t];
#pragma unroll
        for (int j = 0; j < 64; ++j) acc += hid[j] * Wc2[j * 3 + t];
        out[t] = acc;
    }
}

extern "C" void kernel_launch(void* const* d_in, const int* in_sizes, int n_in,
                              void* d_out, int out_size, void* d_ws, size_t ws_size,
                              hipStream_t stream) {
    const float* x       = (const float*)d_in[0];
    const int*   ei      = (const int*)d_in[1];
    const float* attr    = (const float*)d_in[2];
    /* d_in[3] = batch (all zeros) — unused, pool divides by N */
    const float* W1      = (const float*)d_in[4];
    const float* b1      = (const float*)d_in[5];
    const float* W2      = (const float*)d_in[6];
    const float* b2      = (const float*)d_in[7];
    const float* Wc1     = (const float*)d_in[8];
    const float* bc1     = (const float*)d_in[9];
    const float* Wc2     = (const float*)d_in[10];
    const float* bc2     = (const float*)d_in[11];
    const float* h_other = (const float*)d_in[12];
    float* out = (float*)d_out;

    const int N = in_sizes[3];          // batch array has N entries
    const int E = in_sizes[2];          // edge_attr has E entries
    const size_t NH = (size_t)N * 64;

    float* ws   = (float*)d_ws;
    float* buf0 = ws;                   // XW  (then H1@W2)
    float* buf1 = ws + NH;              // agg1/h1 (then agg2/h2)
    float* dinv = ws + 2 * NH;          // N floats (deg, then dinv in place)
    float* pool = dinv + N;             // 64 floats

    const int* rows = ei;
    const int* cols = ei + E;

    // --- normalization coefficients ---
    hipMemsetAsync(dinv, 0, N * sizeof(float), stream);
    k_deg<<<(E + 255) / 256, 256, 0, stream>>>(rows, attr, dinv, E);
    k_dinv<<<(N + 255) / 256, 256, 0, stream>>>(dinv, N);

    // --- layer 1 ---
    k_gemm64<<<(N + 3) / 4, 256, 0, stream>>>(x, W1, buf0, N);
    hipMemsetAsync(buf1, 0, NH * sizeof(float), stream);
    k_agg<<<(E + 3) / 4, 256, 0, stream>>>(buf0, rows, cols, attr, dinv, buf1, E);
    k_post<<<(int)((NH + 255) / 256), 256, 0, stream>>>(buf1, buf0, dinv, b1, N);

    // --- layer 2 --- (buf1 holds h1; GEMM into buf0, then buf1 is reusable)
    k_gemm64<<<(N + 3) / 4, 256, 0, stream>>>(buf1, W2, buf0, N);
    hipMemsetAsync(buf1, 0, NH * sizeof(float), stream);  // stream-ordered after GEMM read
    k_agg<<<(E + 3) / 4, 256, 0, stream>>>(buf0, rows, cols, attr, dinv, buf1, E);
    k_post<<<(int)((NH + 255) / 256), 256, 0, stream>>>(buf1, buf0, dinv, b2, N);

    // --- pool + head ---
    hipMemsetAsync(pool, 0, 64 * sizeof(float), stream);
    k_pool<<<512, 256, 0, stream>>>(buf1, pool, N);
    k_head<<<1, 128, 0, stream>>>(pool, h_other, Wc1, bc1, Wc2, bc2, out, 1.0f / (float)N);
}

// Round 2
// 854.577 us; speedup vs baseline: 1.2177x; 1.2177x over previous
//
#include <hip/hip_runtime.h>
#include <hip/hip_bf16.h>

// ---------------------------------------------------------------------------
// GCN pipeline with device-built CSR (counting sort by destination row):
//   hist(deg,cnt) -> dinv -> scan(rowptr) -> scatter(edat = {col, norm_w})
//   GEMM1 -> aggCSR1(+selfloop+bias+relu) -> GEMM2 -> aggCSR2(+pool fusion)
//   -> head
// H = F = 64 (== wave width). One wave per row in agg; no float atomics on
// the hot path (layer-1 agg writes each row once; layer-2 agg feeds pool).
// ---------------------------------------------------------------------------

// deg[r] += attr ; cnt[r] += 1
__global__ __launch_bounds__(256) void k_hist(const int* __restrict__ rows,
                                              const float* __restrict__ attr,
                                              float* __restrict__ deg,
                                              int* __restrict__ cnt, int E) {
    int e = blockIdx.x * 256 + threadIdx.x;
    if (e < E) {
        int r = rows[e];
        atomicAdd(&deg[r], attr[e]);
        atomicAdd(&cnt[r], 1);
    }
}

// dinv[i] = rsqrt(deg[i] + 1)   (+1 = self-loop weight)
__global__ __launch_bounds__(256) void k_dinv(float* __restrict__ deg, int n) {
    int i = blockIdx.x * 256 + threadIdx.x;
    if (i < n) deg[i] = rsqrtf(deg[i] + 1.0f);
}

// per-block sum of cnt -> bsum[b]
__global__ __launch_bounds__(256) void k_breduce(const int* __restrict__ cnt,
                                                 int* __restrict__ bsum, int n) {
    __shared__ int s[256];
    int t = threadIdx.x, i = blockIdx.x * 256 + t;
    s[t] = (i < n) ? cnt[i] : 0;
    __syncthreads();
    for (int off = 128; off > 0; off >>= 1) {
        if (t < off) s[t] += s[t + off];
        __syncthreads();
    }
    if (t == 0) bsum[blockIdx.x] = s[0];
}

// sequential exclusive scan of bsum (nb <= ~400, single thread is fine)
__global__ void k_bscan(int* __restrict__ bsum, int nb) {
    if (threadIdx.x == 0 && blockIdx.x == 0) {
        int acc = 0;
        for (int b = 0; b < nb; ++b) { int v = bsum[b]; bsum[b] = acc; acc += v; }
    }
}

// per-block exclusive scan of cnt + block offset -> rowptr
__global__ __launch_bounds__(256) void k_cscan(const int* __restrict__ cnt,
                                               const int* __restrict__ bsum,
                                               int* __restrict__ rowptr, int n) {
    __shared__ int tmp[256];
    int t = threadIdx.x, i = blockIdx.x * 256 + t;
    int v = (i < n) ? cnt[i] : 0;
    tmp[t] = v;
    __syncthreads();
    for (int off = 1; off < 256; off <<= 1) {
        int add = (t >= off) ? tmp[t - off] : 0;
        __syncthreads();
        tmp[t] += add;
        __syncthreads();
    }
    if (i < n) rowptr[i] = bsum[blockIdx.x] + tmp[t] - v;
}

// scatter edges into CSR order; edat[pos] = {col, bits(dinv[r]*attr*dinv[c])}
__global__ __launch_bounds__(256) void k_scatter(const int* __restrict__ rows,
                                                 const int* __restrict__ cols,
                                                 const float* __restrict__ attr,
                                                 const float* __restrict__ dinv,
                                                 const int* __restrict__ rowptr,
                                                 int* __restrict__ fill,
                                                 int2* __restrict__ edat, int E) {
    int e = blockIdx.x * 256 + threadIdx.x;
    if (e < E) {
        int r = rows[e], c = cols[e];
        float w = dinv[r] * attr[e] * dinv[c];
        int pos = rowptr[r] + atomicAdd(&fill[r], 1);
        edat[pos] = make_int2(c, __float_as_int(w));
    }
}

// out[n x 64] = in[n x 64] @ W[64 x 64]; 16 rows x 64 cols per block,
// 4 rows per thread (amortize the ws[k][col] LDS read over 4 FMAs).
__global__ __launch_bounds__(256) void k_gemm64(const float* __restrict__ in,
                                                const float* __restrict__ W,
                                                float* __restrict__ out, int n) {
    __shared__ float ws[64][64];
    __shared__ float xs[16][64];
    int t = threadIdx.x;
    for (int i = t; i < 64 * 64; i += 256) ((float*)ws)[i] = W[i];
    int r0 = blockIdx.x * 16;
    for (int i = t; i < 16 * 64; i += 256) {
        int rr = i >> 6;
        if (r0 + rr < n) xs[rr][i & 63] = in[(size_t)(r0 + rr) * 64 + (i & 63)];
    }
    __syncthreads();
    int col = t & 63, q = t >> 6;  // wave q handles rows q*4 .. q*4+3
    float a0 = 0, a1 = 0, a2 = 0, a3 = 0;
#pragma unroll
    for (int k = 0; k < 64; ++k) {
        float w = ws[k][col];
        a0 = fmaf(xs[q * 4 + 0][k], w, a0);
        a1 = fmaf(xs[q * 4 + 1][k], w, a1);
        a2 = fmaf(xs[q * 4 + 2][k], w, a2);
        a3 = fmaf(xs[q * 4 + 3][k], w, a3);
    }
    int row = r0 + q * 4;
    if (row + 0 < n) out[(size_t)(row + 0) * 64 + col] = a0;
    if (row + 1 < n) out[(size_t)(row + 1) * 64 + col] = a1;
    if (row + 2 < n) out[(size_t)(row + 2) * 64 + col] = a2;
    if (row + 3 < n) out[(size_t)(row + 3) * 64 + col] = a3;
}

// Layer-1 aggregation: one wave per row, lane = feature.
// h[r,lane] = relu( sum_e w_e*src[c_e,lane] + dinv[r]^2*src[r,lane] + b[lane] )
__global__ __launch_bounds__(256) void k_aggA(const float* __restrict__ src,
                                              const int* __restrict__ rowptr,
                                              const int* __restrict__ cnt,
                                              const float* __restrict__ dinv,
                                              const int2* __restrict__ edat,
                                              const float* __restrict__ b,
                                              float* __restrict__ out, int n) {
    int r = blockIdx.x * 4 + (threadIdx.x >> 6);
    int lane = threadIdx.x & 63;
    if (r >= n) return;
    int s = rowptr[r], len = cnt[r];
    float acc = 0.0f;
    for (int j = 0; j < len; ++j) {
        int2 m = edat[s + j];  // wave-uniform broadcast load
        acc = fmaf(__int_as_float(m.y), src[((size_t)m.x << 6) | lane], acc);
    }
    float d = dinv[r];
    float v = acc + d * d * src[((size_t)r << 6) | lane] + b[lane];
    out[((size_t)r << 6) | lane] = v > 0.0f ? v : 0.0f;
}

// Layer-2 aggregation fused with mean-pool: never materializes h2.
// pool[lane] += sum_r relu( agg_r + d^2*src[r] + b )
__global__ __launch_bounds__(256) void k_aggB(const float* __restrict__ src,
                                              const int* __restrict__ rowptr,
                                              const int* __restrict__ cnt,
                                              const float* __restrict__ dinv,
                                              const int2* __restrict__ edat,
                                              const float* __restrict__ b,
                                              float* __restrict__ pool, int n) {
    __shared__ float part[4][64];
    int wv = threadIdx.x >> 6, lane = threadIdx.x & 63;
    float pacc = 0.0f;
    for (int r = blockIdx.x * 4 + wv; r < n; r += gridDim.x * 4) {
        int s = rowptr[r], len = cnt[r];
        float acc = 0.0f;
        for (int j = 0; j < len; ++j) {
            int2 m = edat[s + j];
            acc = fmaf(__int_as_float(m.y), src[((size_t)m.x << 6) | lane], acc);
        }
        float d = dinv[r];
        float v = acc + d * d * src[((size_t)r << 6) | lane] + b[lane];
        pacc += v > 0.0f ? v : 0.0f;
    }
    part[wv][lane] = pacc;
    __syncthreads();
    if (wv == 0) {
        float s = part[0][lane] + part[1][lane] + part[2][lane] + part[3][lane];
        atomicAdd(&pool[lane], s);
    }
}

// z = [pool/N, h_other]; out = relu(z @ Wc1 + bc1) @ Wc2 + bc2
__global__ __launch_bounds__(128) void k_head(const float* __restrict__ pool,
                                              const float* __restrict__ h_other,
                                              const float* __restrict__ Wc1,
                                              const float* __restrict__ bc1,
                                              const float* __restrict__ Wc2,
                                              const float* __restrict__ bc2,
                                              float* __restrict__ out, float invN) {
    __shared__ float z[128];
    __shared__ float hid[64];
    int t = threadIdx.x;
    z[t] = (t < 64) ? pool[t] * invN : h_other[t - 64];
    __syncthreads();
    if (t < 64) {
        float acc = bc1[t];
#pragma unroll
        for (int k = 0; k < 128; ++k) acc += z[k] * Wc1[k * 64 + t];
        hid[t] = acc > 0.0f ? acc : 0.0f;
    }
    __syncthreads();
    if (t < 3) {
        float acc = bc2[t];
#pragma unroll
        for (int j = 0; j < 64; ++j) acc += hid[j] * Wc2[j * 3 + t];
        out[t] = acc;
    }
}

extern "C" void kernel_launch(void* const* d_in, const int* in_sizes, int n_in,
                              void* d_out, int out_size, void* d_ws, size_t ws_size,
                              hipStream_t stream) {
    const float* x       = (const float*)d_in[0];
    const int*   ei      = (const int*)d_in[1];
    const float* attr    = (const float*)d_in[2];
    const float* W1      = (const float*)d_in[4];
    const float* b1      = (const float*)d_in[5];
    const float* W2      = (const float*)d_in[6];
    const float* b2      = (const float*)d_in[7];
    const float* Wc1     = (const float*)d_in[8];
    const float* bc1     = (const float*)d_in[9];
    const float* Wc2     = (const float*)d_in[10];
    const float* bc2     = (const float*)d_in[11];
    const float* h_other = (const float*)d_in[12];
    float* out = (float*)d_out;

    const int N = in_sizes[3];
    const int E = in_sizes[2];
    const size_t NH = (size_t)N * 64;
    const int NB = (N + 255) / 256;

    float* ws0  = (float*)d_ws;
    float* buf0 = ws0;                    // NH : XW1, then H1@W2
    float* buf1 = buf0 + NH;              // NH : h1
    float* dinv = buf1 + NH;              // N  : deg then dinv
    float* pool = dinv + N;               // 64
    int* cnt    = (int*)(pool + 64);      // N
    int* rowptr = cnt + N;                // N
    int* fill   = rowptr + N;             // N
    int* bsum   = fill + N;               // 1024 (NB <= 1024)
    int2* edat  = (int2*)(bsum + 1024);   // E  (offset is 8B-aligned)

    const int* rows = ei;
    const int* cols = ei + E;

    // zero deg/pool/cnt/rowptr/fill/bsum in one shot (contiguous)
    hipMemsetAsync(dinv, 0, (size_t)(4 * N + 64 + 1024) * sizeof(float), stream);

    // --- CSR build (shared by both layers) ---
    k_hist<<<(E + 255) / 256, 256, 0, stream>>>(rows, attr, dinv, cnt, E);
    k_dinv<<<(N + 255) / 256, 256, 0, stream>>>(dinv, N);
    k_breduce<<<NB, 256, 0, stream>>>(cnt, bsum, N);
    k_bscan<<<1, 64, 0, stream>>>(bsum, NB);
    k_cscan<<<NB, 256, 0, stream>>>(cnt, bsum, rowptr, N);
    k_scatter<<<(E + 255) / 256, 256, 0, stream>>>(rows, cols, attr, dinv, rowptr,
                                                   fill, edat, E);

    // --- layer 1 ---
    k_gemm64<<<(N + 15) / 16, 256, 0, stream>>>(x, W1, buf0, N);
    k_aggA<<<(N + 3) / 4, 256, 0, stream>>>(buf0, rowptr, cnt, dinv, edat, b1, buf1, N);

    // --- layer 2 (agg fused with mean-pool; h2 never materialized) ---
    k_gemm64<<<(N + 15) / 16, 256, 0, stream>>>(buf1, W2, buf0, N);
    k_aggB<<<2048, 256, 0, stream>>>(buf0, rowptr, cnt, dinv, edat, b2, pool, N);

    // --- head ---
    k_head<<<1, 128, 0, stream>>>(pool, h_other, Wc1, bc1, Wc2, bc2, out,
                                  1.0f / (float)N);
}

// Round 3
// 571.082 us; speedup vs baseline: 1.8222x; 1.4964x over previous
//
#include <hip/hip_runtime.h>
#include <hip/hip_bf16.h>

// ---------------------------------------------------------------------------
// GCN pipeline with device-built CSR (counting sort by destination row):
//   hist(deg,cnt) -> dinv -> scan(rowptr) -> scatter(edat = {col, norm_w})
//   GEMM1 -> aggCSR1(+selfloop+bias+relu) -> GEMM2 -> aggCSR2(+pool fusion)
//   -> head
// H = F = 64 (== wave width). One wave per row in agg, edge loop unrolled x4
// with 4 independent accumulators -> 4 gathers in flight per wave (the R2
// profile showed latency-bound: 1 outstanding gather, VALUBusy 15%).
// ---------------------------------------------------------------------------

__global__ __launch_bounds__(256) void k_hist(const int* __restrict__ rows,
                                              const float* __restrict__ attr,
                                              float* __restrict__ deg,
                                              int* __restrict__ cnt, int E) {
    int e = blockIdx.x * 256 + threadIdx.x;
    if (e < E) {
        int r = rows[e];
        atomicAdd(&deg[r], attr[e]);
        atomicAdd(&cnt[r], 1);
    }
}

__global__ __launch_bounds__(256) void k_dinv(float* __restrict__ deg, int n) {
    int i = blockIdx.x * 256 + threadIdx.x;
    if (i < n) deg[i] = rsqrtf(deg[i] + 1.0f);
}

__global__ __launch_bounds__(256) void k_breduce(const int* __restrict__ cnt,
                                                 int* __restrict__ bsum, int n) {
    __shared__ int s[256];
    int t = threadIdx.x, i = blockIdx.x * 256 + t;
    s[t] = (i < n) ? cnt[i] : 0;
    __syncthreads();
    for (int off = 128; off > 0; off >>= 1) {
        if (t < off) s[t] += s[t + off];
        __syncthreads();
    }
    if (t == 0) bsum[blockIdx.x] = s[0];
}

__global__ void k_bscan(int* __restrict__ bsum, int nb) {
    if (threadIdx.x == 0 && blockIdx.x == 0) {
        int acc = 0;
        for (int b = 0; b < nb; ++b) { int v = bsum[b]; bsum[b] = acc; acc += v; }
    }
}

__global__ __launch_bounds__(256) void k_cscan(const int* __restrict__ cnt,
                                               const int* __restrict__ bsum,
                                               int* __restrict__ rowptr, int n) {
    __shared__ int tmp[256];
    int t = threadIdx.x, i = blockIdx.x * 256 + t;
    int v = (i < n) ? cnt[i] : 0;
    tmp[t] = v;
    __syncthreads();
    for (int off = 1; off < 256; off <<= 1) {
        int add = (t >= off) ? tmp[t - off] : 0;
        __syncthreads();
        tmp[t] += add;
        __syncthreads();
    }
    if (i < n) rowptr[i] = bsum[blockIdx.x] + tmp[t] - v;
}

__global__ __launch_bounds__(256) void k_scatter(const int* __restrict__ rows,
                                                 const int* __restrict__ cols,
                                                 const float* __restrict__ attr,
                                                 const float* __restrict__ dinv,
                                                 const int* __restrict__ rowptr,
                                                 int* __restrict__ fill,
                                                 int2* __restrict__ edat, int E) {
    int e = blockIdx.x * 256 + threadIdx.x;
    if (e < E) {
        int r = rows[e], c = cols[e];
        float w = dinv[r] * attr[e] * dinv[c];
        int pos = rowptr[r] + atomicAdd(&fill[r], 1);
        edat[pos] = make_int2(c, __float_as_int(w));
    }
}

// out[n x 64] = in[n x 64] @ W[64 x 64]; 16 rows/block, each thread computes
// 1 row x 4 contiguous cols: float4 LDS reads of W, float4 global load/store.
__global__ __launch_bounds__(256) void k_gemm64(const float* __restrict__ in,
                                                const float* __restrict__ W,
                                                float* __restrict__ out, int n) {
    __shared__ float4 ws4[64][16];
    __shared__ float xs[16][64];
    int t = threadIdx.x;
    const float4* W4 = (const float4*)W;
    for (int i = t; i < 1024; i += 256) ((float4*)ws4)[i] = W4[i];
    int r0 = blockIdx.x * 16;
    int rr = t >> 4, c4 = t & 15;
    if (r0 + rr < n)
        ((float4*)xs)[t] = ((const float4*)in)[(size_t)(r0 + rr) * 16 + c4];
    __syncthreads();
    if (r0 + rr < n) {
        float4 acc = {0.f, 0.f, 0.f, 0.f};
#pragma unroll
        for (int k = 0; k < 64; ++k) {
            float xv = xs[rr][k];
            float4 wv = ws4[k][c4];
            acc.x = fmaf(xv, wv.x, acc.x);
            acc.y = fmaf(xv, wv.y, acc.y);
            acc.z = fmaf(xv, wv.z, acc.z);
            acc.w = fmaf(xv, wv.w, acc.w);
        }
        ((float4*)out)[(size_t)(r0 + rr) * 16 + c4] = acc;
    }
}

// Layer-1 aggregation: one wave per row, lane = feature. Edge loop unrolled
// x4 with independent accumulators (4 gathers in flight).
__global__ __launch_bounds__(256) void k_aggA(const float* __restrict__ src,
                                              const int* __restrict__ rowptr,
                                              const int* __restrict__ cnt,
                                              const float* __restrict__ dinv,
                                              const int2* __restrict__ edat,
                                              const float* __restrict__ b,
                                              float* __restrict__ out, int n) {
    int r = blockIdx.x * 4 + (threadIdx.x >> 6);
    int lane = threadIdx.x & 63;
    if (r >= n) return;
    int s = rowptr[r], len = cnt[r];
    const int2* ep = edat + s;
    float a0 = 0.f, a1 = 0.f, a2 = 0.f, a3 = 0.f;
    int nr = len >> 2;
    for (int t = 0; t < nr; ++t) {
        int2 m0 = ep[4 * t + 0];
        int2 m1 = ep[4 * t + 1];
        int2 m2 = ep[4 * t + 2];
        int2 m3 = ep[4 * t + 3];
        a0 = fmaf(__int_as_float(m0.y), src[((size_t)m0.x << 6) | lane], a0);
        a1 = fmaf(__int_as_float(m1.y), src[((size_t)m1.x << 6) | lane], a1);
        a2 = fmaf(__int_as_float(m2.y), src[((size_t)m2.x << 6) | lane], a2);
        a3 = fmaf(__int_as_float(m3.y), src[((size_t)m3.x << 6) | lane], a3);
    }
    for (int j = nr * 4; j < len; ++j) {
        int2 m = ep[j];
        a0 = fmaf(__int_as_float(m.y), src[((size_t)m.x << 6) | lane], a0);
    }
    float acc = (a0 + a1) + (a2 + a3);
    float d = dinv[r];
    float v = acc + d * d * src[((size_t)r << 6) | lane] + b[lane];
    out[((size_t)r << 6) | lane] = v > 0.0f ? v : 0.0f;
}

// Layer-2 aggregation fused with mean-pool (h2 never materialized), same x4
// unroll. pool[lane] += sum_r relu(...)
__global__ __launch_bounds__(256) void k_aggB(const float* __restrict__ src,
                                              const int* __restrict__ rowptr,
                                              const int* __restrict__ cnt,
                                              const float* __restrict__ dinv,
                                              const int2* __restrict__ edat,
                                              const float* __restrict__ b,
                                              float* __restrict__ pool, int n) {
    __shared__ float part[4][64];
    int wv = threadIdx.x >> 6, lane = threadIdx.x & 63;
    float pacc = 0.0f;
    for (int r = blockIdx.x * 4 + wv; r < n; r += gridDim.x * 4) {
        int s = rowptr[r], len = cnt[r];
        const int2* ep = edat + s;
        float a0 = 0.f, a1 = 0.f, a2 = 0.f, a3 = 0.f;
        int nr = len >> 2;
        for (int t = 0; t < nr; ++t) {
            int2 m0 = ep[4 * t + 0];
            int2 m1 = ep[4 * t + 1];
            int2 m2 = ep[4 * t + 2];
            int2 m3 = ep[4 * t + 3];
            a0 = fmaf(__int_as_float(m0.y), src[((size_t)m0.x << 6) | lane], a0);
            a1 = fmaf(__int_as_float(m1.y), src[((size_t)m1.x << 6) | lane], a1);
            a2 = fmaf(__int_as_float(m2.y), src[((size_t)m2.x << 6) | lane], a2);
            a3 = fmaf(__int_as_float(m3.y), src[((size_t)m3.x << 6) | lane], a3);
        }
        for (int j = nr * 4; j < len; ++j) {
            int2 m = ep[j];
            a0 = fmaf(__int_as_float(m.y), src[((size_t)m.x << 6) | lane], a0);
        }
        float acc = (a0 + a1) + (a2 + a3);
        float d = dinv[r];
        float v = acc + d * d * src[((size_t)r << 6) | lane] + b[lane];
        pacc += v > 0.0f ? v : 0.0f;
    }
    part[wv][lane] = pacc;
    __syncthreads();
    if (wv == 0) {
        float s = part[0][lane] + part[1][lane] + part[2][lane] + part[3][lane];
        atomicAdd(&pool[lane], s);
    }
}

__global__ __launch_bounds__(128) void k_head(const float* __restrict__ pool,
                                              const float* __restrict__ h_other,
                                              const float* __restrict__ Wc1,
                                              const float* __restrict__ bc1,
                                              const float* __restrict__ Wc2,
                                              const float* __restrict__ bc2,
                                              float* __restrict__ out, float invN) {
    __shared__ float z[128];
    __shared__ float hid[64];
    int t = threadIdx.x;
    z[t] = (t < 64) ? pool[t] * invN : h_other[t - 64];
    __syncthreads();
    if (t < 64) {
        float acc = bc1[t];
#pragma unroll
        for (int k = 0; k < 128; ++k) acc += z[k] * Wc1[k * 64 + t];
        hid[t] = acc > 0.0f ? acc : 0.0f;
    }
    __syncthreads();
    if (t < 3) {
        float acc = bc2[t];
#pragma unroll
        for (int j = 0; j < 64; ++j) acc += hid[j] * Wc2[j * 3 + t];
        out[t] = acc;
    }
}

extern "C" void kernel_launch(void* const* d_in, const int* in_sizes, int n_in,
                              void* d_out, int out_size, void* d_ws, size_t ws_size,
                              hipStream_t stream) {
    const float* x       = (const float*)d_in[0];
    const int*   ei      = (const int*)d_in[1];
    const float* attr    = (const float*)d_in[2];
    const float* W1      = (const float*)d_in[4];
    const float* b1      = (const float*)d_in[5];
    const float* W2      = (const float*)d_in[6];
    const float* b2      = (const float*)d_in[7];
    const float* Wc1     = (const float*)d_in[8];
    const float* bc1     = (const float*)d_in[9];
    const float* Wc2     = (const float*)d_in[10];
    const float* bc2     = (const float*)d_in[11];
    const float* h_other = (const float*)d_in[12];
    float* out = (float*)d_out;

    const int N = in_sizes[3];
    const int E = in_sizes[2];
    const size_t NH = (size_t)N * 64;
    const int NB = (N + 255) / 256;

    float* ws0  = (float*)d_ws;
    float* buf0 = ws0;                    // NH : XW1, then H1@W2
    float* buf1 = buf0 + NH;              // NH : h1
    float* dinv = buf1 + NH;              // N  : deg then dinv
    float* pool = dinv + N;               // 64
    int* cnt    = (int*)(pool + 64);      // N
    int* rowptr = cnt + N;                // N
    int* fill   = rowptr + N;             // N
    int* bsum   = fill + N;               // 1024 (NB <= 1024)
    int2* edat  = (int2*)(bsum + 1024);   // E

    const int* rows = ei;
    const int* cols = ei + E;

    hipMemsetAsync(dinv, 0, (size_t)(4 * N + 64 + 1024) * sizeof(float), stream);

    // --- CSR build (shared by both layers) ---
    k_hist<<<(E + 255) / 256, 256, 0, stream>>>(rows, attr, dinv, cnt, E);
    k_dinv<<<(N + 255) / 256, 256, 0, stream>>>(dinv, N);
    k_breduce<<<NB, 256, 0, stream>>>(cnt, bsum, N);
    k_bscan<<<1, 64, 0, stream>>>(bsum, NB);
    k_cscan<<<NB, 256, 0, stream>>>(cnt, bsum, rowptr, N);
    k_scatter<<<(E + 255) / 256, 256, 0, stream>>>(rows, cols, attr, dinv, rowptr,
                                                   fill, edat, E);

    // --- layer 1 ---
    k_gemm64<<<(N + 15) / 16, 256, 0, stream>>>(x, W1, buf0, N);
    k_aggA<<<(N + 3) / 4, 256, 0, stream>>>(buf0, rowptr, cnt, dinv, edat, b1, buf1, N);

    // --- layer 2 (agg fused with mean-pool) ---
    k_gemm64<<<(N + 15) / 16, 256, 0, stream>>>(buf1, W2, buf0, N);
    k_aggB<<<2048, 256, 0, stream>>>(buf0, rowptr, cnt, dinv, edat, b2, pool, N);

    // --- head ---
    k_head<<<1, 128, 0, stream>>>(pool, h_other, Wc1, bc1, Wc2, bc2, out,
                                  1.0f / (float)N);
}

// Round 4
// 442.359 us; speedup vs baseline: 2.3524x; 1.2910x over previous
//
#include <hip/hip_runtime.h>
#include <hip/hip_bf16.h>

// ---------------------------------------------------------------------------
// GCN pipeline with device-built ELL bucket adjacency (ONE atomic per edge):
//   bucket(fill,edat={col,attr}) -> degsum(dinv) ->
//   GEMM1 -> aggELL1(+selfloop+bias+relu) -> GEMM2 -> aggELL2(+pool fusion)
//   -> head
// H = F = 64 (== wave width). Normalization dinv[r]*attr*dinv[c] is applied
// inside agg (dinv gather is L2-resident and hides under the src gather).
// fill[] counters are 64B-strided: R3 showed the histogram atomics were
// line-contention bound (256 atomics/line, VALUBusy 0.3%, 100MB write-through).
// ---------------------------------------------------------------------------

#define CAP 48       // max degree capacity (Poisson(16): P(overflow) ~ 8e-6)
#define FSTRIDE 16   // fill stride in ints = 64B -> one cache line per counter

// pos = fill[r]++; edat[r*CAP+pos] = {col, attr_bits}
__global__ __launch_bounds__(256) void k_bucket(const int* __restrict__ rows,
                                                const int* __restrict__ cols,
                                                const float* __restrict__ attr,
                                                int* __restrict__ fill,
                                                int2* __restrict__ edat, int E) {
    int e = blockIdx.x * 256 + threadIdx.x;
    if (e < E) {
        int r = rows[e];
        int pos = atomicAdd(&fill[r * FSTRIDE], 1);
        if (pos < CAP)
            edat[(size_t)r * CAP + pos] = make_int2(cols[e], __float_as_int(attr[e]));
    }
}

// wave per row: dinv[r] = rsqrt(1 + sum_j attr_j)   (shuffle reduction)
__global__ __launch_bounds__(256) void k_degsum(const int* __restrict__ fill,
                                                const int2* __restrict__ edat,
                                                float* __restrict__ dinv, int n) {
    int wv = threadIdx.x >> 6, lane = threadIdx.x & 63;
    int r = blockIdx.x * 4 + wv;
    if (r >= n) return;
    int len = min(fill[r * FSTRIDE], CAP);
    float v = (lane < len) ? __int_as_float(edat[(size_t)r * CAP + lane].y) : 0.0f;
#pragma unroll
    for (int off = 32; off > 0; off >>= 1) v += __shfl_down(v, off, 64);
    if (lane == 0) dinv[r] = rsqrtf(v + 1.0f);
}

// out[n x 64] = in[n x 64] @ W[64 x 64]; 16 rows/block, each thread computes
// 1 row x 4 contiguous cols: float4 LDS reads of W, float4 global load/store.
__global__ __launch_bounds__(256) void k_gemm64(const float* __restrict__ in,
                                                const float* __restrict__ W,
                                                float* __restrict__ out, int n) {
    __shared__ float4 ws4[64][16];
    __shared__ float xs[16][64];
    int t = threadIdx.x;
    const float4* W4 = (const float4*)W;
    for (int i = t; i < 1024; i += 256) ((float4*)ws4)[i] = W4[i];
    int r0 = blockIdx.x * 16;
    int rr = t >> 4, c4 = t & 15;
    if (r0 + rr < n)
        ((float4*)xs)[t] = ((const float4*)in)[(size_t)(r0 + rr) * 16 + c4];
    __syncthreads();
    if (r0 + rr < n) {
        float4 acc = {0.f, 0.f, 0.f, 0.f};
#pragma unroll
        for (int k = 0; k < 64; ++k) {
            float xv = xs[rr][k];
            float4 wv = ws4[k][c4];
            acc.x = fmaf(xv, wv.x, acc.x);
            acc.y = fmaf(xv, wv.y, acc.y);
            acc.z = fmaf(xv, wv.z, acc.z);
            acc.w = fmaf(xv, wv.w, acc.w);
        }
        ((float4*)out)[(size_t)(r0 + rr) * 16 + c4] = acc;
    }
}

// Layer-1 aggregation: one wave per row, lane = feature, x4 unroll (4 gathers
// in flight). w_e = dinv[r]*attr_e*dinv[c_e] computed in-loop (dinv is
// L2-resident; its load hides under the 256B src gather).
__global__ __launch_bounds__(256) void k_aggA(const float* __restrict__ src,
                                              const int* __restrict__ fill,
                                              const float* __restrict__ dinv,
                                              const int2* __restrict__ edat,
                                              const float* __restrict__ b,
                                              float* __restrict__ out, int n) {
    int r = blockIdx.x * 4 + (threadIdx.x >> 6);
    int lane = threadIdx.x & 63;
    if (r >= n) return;
    int len = min(fill[r * FSTRIDE], CAP);
    float dr = dinv[r];
    const int2* ep = edat + (size_t)r * CAP;
    float a0 = 0.f, a1 = 0.f, a2 = 0.f, a3 = 0.f;
    int nr = len >> 2;
    for (int t = 0; t < nr; ++t) {
        int2 m0 = ep[4 * t + 0];
        int2 m1 = ep[4 * t + 1];
        int2 m2 = ep[4 * t + 2];
        int2 m3 = ep[4 * t + 3];
        float w0 = dr * __int_as_float(m0.y) * dinv[m0.x];
        float w1 = dr * __int_as_float(m1.y) * dinv[m1.x];
        float w2 = dr * __int_as_float(m2.y) * dinv[m2.x];
        float w3 = dr * __int_as_float(m3.y) * dinv[m3.x];
        a0 = fmaf(w0, src[((size_t)m0.x << 6) | lane], a0);
        a1 = fmaf(w1, src[((size_t)m1.x << 6) | lane], a1);
        a2 = fmaf(w2, src[((size_t)m2.x << 6) | lane], a2);
        a3 = fmaf(w3, src[((size_t)m3.x << 6) | lane], a3);
    }
    for (int j = nr * 4; j < len; ++j) {
        int2 m = ep[j];
        float w = dr * __int_as_float(m.y) * dinv[m.x];
        a0 = fmaf(w, src[((size_t)m.x << 6) | lane], a0);
    }
    float acc = (a0 + a1) + (a2 + a3);
    float v = acc + dr * dr * src[((size_t)r << 6) | lane] + b[lane];
    out[((size_t)r << 6) | lane] = v > 0.0f ? v : 0.0f;
}

// Layer-2 aggregation fused with mean-pool (h2 never materialized).
__global__ __launch_bounds__(256) void k_aggB(const float* __restrict__ src,
                                              const int* __restrict__ fill,
                                              const float* __restrict__ dinv,
                                              const int2* __restrict__ edat,
                                              const float* __restrict__ b,
                                              float* __restrict__ pool, int n) {
    __shared__ float part[4][64];
    int wv = threadIdx.x >> 6, lane = threadIdx.x & 63;
    float pacc = 0.0f;
    for (int r = blockIdx.x * 4 + wv; r < n; r += gridDim.x * 4) {
        int len = min(fill[r * FSTRIDE], CAP);
        float dr = dinv[r];
        const int2* ep = edat + (size_t)r * CAP;
        float a0 = 0.f, a1 = 0.f, a2 = 0.f, a3 = 0.f;
        int nr = len >> 2;
        for (int t = 0; t < nr; ++t) {
            int2 m0 = ep[4 * t + 0];
            int2 m1 = ep[4 * t + 1];
            int2 m2 = ep[4 * t + 2];
            int2 m3 = ep[4 * t + 3];
            float w0 = dr * __int_as_float(m0.y) * dinv[m0.x];
            float w1 = dr * __int_as_float(m1.y) * dinv[m1.x];
            float w2 = dr * __int_as_float(m2.y) * dinv[m2.x];
            float w3 = dr * __int_as_float(m3.y) * dinv[m3.x];
            a0 = fmaf(w0, src[((size_t)m0.x << 6) | lane], a0);
            a1 = fmaf(w1, src[((size_t)m1.x << 6) | lane], a1);
            a2 = fmaf(w2, src[((size_t)m2.x << 6) | lane], a2);
            a3 = fmaf(w3, src[((size_t)m3.x << 6) | lane], a3);
        }
        for (int j = nr * 4; j < len; ++j) {
            int2 m = ep[j];
            float w = dr * __int_as_float(m.y) * dinv[m.x];
            a0 = fmaf(w, src[((size_t)m.x << 6) | lane], a0);
        }
        float acc = (a0 + a1) + (a2 + a3);
        float v = acc + dr * dr * src[((size_t)r << 6) | lane] + b[lane];
        pacc += v > 0.0f ? v : 0.0f;
    }
    part[wv][lane] = pacc;
    __syncthreads();
    if (wv == 0) {
        float s = part[0][lane] + part[1][lane] + part[2][lane] + part[3][lane];
        atomicAdd(&pool[lane], s);
    }
}

// z = [pool/N, h_other]; out = relu(z @ Wc1 + bc1) @ Wc2 + bc2
__global__ __launch_bounds__(128) void k_head(const float* __restrict__ pool,
                                              const float* __restrict__ h_other,
                                              const float* __restrict__ Wc1,
                                              const float* __restrict__ bc1,
                                              const float* __restrict__ Wc2,
                                              const float* __restrict__ bc2,
                                              float* __restrict__ out, float invN) {
    __shared__ float z[128];
    __shared__ float hid[64];
    int t = threadIdx.x;
    z[t] = (t < 64) ? pool[t] * invN : h_other[t - 64];
    __syncthreads();
    if (t < 64) {
        float acc = bc1[t];
#pragma unroll
        for (int k = 0; k < 128; ++k) acc += z[k] * Wc1[k * 64 + t];
        hid[t] = acc > 0.0f ? acc : 0.0f;
    }
    __syncthreads();
    if (t < 3) {
        float acc = bc2[t];
#pragma unroll
        for (int j = 0; j < 64; ++j) acc += hid[j] * Wc2[j * 3 + t];
        out[t] = acc;
    }
}

extern "C" void kernel_launch(void* const* d_in, const int* in_sizes, int n_in,
                              void* d_out, int out_size, void* d_ws, size_t ws_size,
                              hipStream_t stream) {
    const float* x       = (const float*)d_in[0];
    const int*   ei      = (const int*)d_in[1];
    const float* attr    = (const float*)d_in[2];
    const float* W1      = (const float*)d_in[4];
    const float* b1      = (const float*)d_in[5];
    const float* W2      = (const float*)d_in[6];
    const float* b2      = (const float*)d_in[7];
    const float* Wc1     = (const float*)d_in[8];
    const float* bc1     = (const float*)d_in[9];
    const float* Wc2     = (const float*)d_in[10];
    const float* bc2     = (const float*)d_in[11];
    const float* h_other = (const float*)d_in[12];
    float* out = (float*)d_out;

    const int N = in_sizes[3];
    const int E = in_sizes[2];
    const size_t NH = (size_t)N * 64;

    // workspace layout (floats):
    //   buf0[NH] | buf1[NH] | dinv[N] | pool[64] | fill[16N ints] | edat[CAP*N int2]
    float* ws0  = (float*)d_ws;
    float* buf0 = ws0;
    float* buf1 = buf0 + NH;
    float* dinv = buf1 + NH;
    float* pool = dinv + N;
    int*   fill = (int*)(pool + 64);
    int2*  edat = (int2*)(fill + (size_t)N * FSTRIDE);   // 8B-aligned (even float count)

    const int* rows = ei;
    const int* cols = ei + E;

    // zero pool + fill in one contiguous memset
    hipMemsetAsync(pool, 0, (64 + (size_t)N * FSTRIDE) * sizeof(int), stream);

    // --- ELL adjacency build (shared by both layers) ---
    k_bucket<<<(E + 255) / 256, 256, 0, stream>>>(rows, cols, attr, fill, edat, E);
    k_degsum<<<(N + 3) / 4, 256, 0, stream>>>(fill, edat, dinv, N);

    // --- layer 1 ---
    k_gemm64<<<(N + 15) / 16, 256, 0, stream>>>(x, W1, buf0, N);
    k_aggA<<<(N + 3) / 4, 256, 0, stream>>>(buf0, fill, dinv, edat, b1, buf1, N);

    // --- layer 2 (agg fused with mean-pool) ---
    k_gemm64<<<(N + 15) / 16, 256, 0, stream>>>(buf1, W2, buf0, N);
    k_aggB<<<2048, 256, 0, stream>>>(buf0, fill, dinv, edat, b2, pool, N);

    // --- head ---
    k_head<<<1, 128, 0, stream>>>(pool, h_other, Wc1, bc1, Wc2, bc2, out,
                                  1.0f / (float)N);
}

// Round 5
// 353.715 us; speedup vs baseline: 2.9420x; 1.2506x over previous
//
#include <hip/hip_runtime.h>
#include <hip/hip_bf16.h>

// ---------------------------------------------------------------------------
// GCN pipeline, adjacency built via two-pass partitioned counting sort:
//   k_part : edges -> 196 row-partitions (LDS ranks, ONE global atomic per
//            block-partition; R4 showed per-edge device atomics = 64B random
//            HBM line each => 100 MB write-through, 0.93 TB/s ceiling)
//   k_build: per-partition LDS sort -> contiguous CSR adj[] + meta + dinv
//   GEMM1 -> aggCSR1(+selfloop+bias+relu) -> GEMM2 -> aggCSR2(+pool) -> head
// H = F = 64 (== wave width). Agg: wave/row, x4-unrolled gathers.
// ---------------------------------------------------------------------------

#define PSHIFT 9
#define PRWS   512           // rows per partition
#define PCAP   10240         // slots per partition (mean 8192, +22 sigma)
#define PFS    16            // pfill stride (ints) = one 64B line per counter
#define VT     4             // edges per thread in k_part

// Pass 1: partition edges. Block = 1024 thr x 4 edges. LDS histogram over
// partitions -> per-edge local rank; one global atomicAdd per (block,part).
__global__ __launch_bounds__(1024) void k_part(const int* __restrict__ rows,
                                               const int* __restrict__ cols,
                                               const float* __restrict__ attr,
                                               int* __restrict__ pfill,
                                               unsigned long long* __restrict__ region,
                                               int E) {
    __shared__ int cntS[256];
    __shared__ int baseS[256];
    int t = threadIdx.x;
    if (t < 256) cntS[t] = 0;
    __syncthreads();
    int e0 = blockIdx.x * (1024 * VT);
    int pa[VT], ra[VT];
    unsigned long long rec[VT];
#pragma unroll
    for (int i = 0; i < VT; ++i) {
        int e = e0 + i * 1024 + t;
        if (e < E) {
            int r = rows[e];
            int p = r >> PSHIFT;
            pa[i]  = p;
            rec[i] = ((unsigned long long)__float_as_uint(attr[e]) << 32) |
                     ((unsigned)(r & (PRWS - 1)) << 17) | (unsigned)cols[e];
            ra[i]  = atomicAdd(&cntS[p], 1);            // LDS atomic
        } else pa[i] = -1;
    }
    __syncthreads();
    if (t < 256 && cntS[t] > 0)
        baseS[t] = atomicAdd(&pfill[t * PFS], cntS[t]); // one global atomic
    __syncthreads();
#pragma unroll
    for (int i = 0; i < VT; ++i) {
        if (pa[i] >= 0) {
            int pos = baseS[pa[i]] + ra[i];
            if (pos < PCAP)
                region[(size_t)pa[i] * PCAP + pos] = rec[i];
        }
    }
}

// Pass 2: one block per partition. LDS row-histogram + attr sums -> scan ->
// coalesced CSR placement into adj[]; also emits dinv and meta=(start<<8)|cnt.
__global__ __launch_bounds__(1024) void k_build(unsigned long long* __restrict__ region,
                                                const int* __restrict__ pfill,
                                                int2* __restrict__ adj,
                                                float* __restrict__ dinv,
                                                int* __restrict__ meta, int N) {
    __shared__ int   cntS[PRWS];
    __shared__ int   c2S[PRWS];
    __shared__ float asum[PRWS];
    __shared__ int   scan[PRWS];
    int p = blockIdx.x, t = threadIdx.x;
    int len = min(pfill[p * PFS], PCAP);
    if (t < PRWS) { cntS[t] = 0; c2S[t] = 0; asum[t] = 0.0f; }
    __syncthreads();
    const unsigned long long* base = region + (size_t)p * PCAP;
    // phase 1: histogram + weighted degree
    for (int j = t; j < len; j += 1024) {
        unsigned long long v = base[j];
        int rl = (int)((v >> 17) & (PRWS - 1));
        atomicAdd(&cntS[rl], 1);
        atomicAdd(&asum[rl], __uint_as_float((unsigned)(v >> 32)));
    }
    __syncthreads();
    // inclusive Hillis-Steele scan of cntS -> scan[]
    if (t < PRWS) scan[t] = cntS[t];
    __syncthreads();
    for (int off = 1; off < PRWS; off <<= 1) {
        int v = 0;
        if (t < PRWS && t >= off) v = scan[t - off];
        __syncthreads();
        if (t < PRWS) scan[t] += v;
        __syncthreads();
    }
    int r0 = p * PRWS;
    if (t < PRWS) {
        int r = r0 + t;
        if (r < N) {
            int start = p * PCAP + (scan[t] - cntS[t]);   // exclusive offset
            meta[r] = (start << 8) | min(cntS[t], 255);
            dinv[r] = rsqrtf(1.0f + asum[t]);
        }
    }
    __syncthreads();
    // phase 2: re-read records, place into adj (coalesced-ish, LDS ranks)
    for (int j = t; j < len; j += 1024) {
        unsigned long long v = base[j];
        int rl   = (int)((v >> 17) & (PRWS - 1));
        int rank = atomicAdd(&c2S[rl], 1);
        int dst  = p * PCAP + (scan[rl] - cntS[rl]) + rank;
        adj[dst] = make_int2((int)(v & 0x1FFFF), (int)(v >> 32));
    }
}

// out[n x 64] = in[n x 64] @ W[64 x 64]; 16 rows/block, thread = 1 row x 4 cols.
__global__ __launch_bounds__(256) void k_gemm64(const float* __restrict__ in,
                                                const float* __restrict__ W,
                                                float* __restrict__ out, int n) {
    __shared__ float4 ws4[64][16];
    __shared__ float xs[16][64];
    int t = threadIdx.x;
    const float4* W4 = (const float4*)W;
    for (int i = t; i < 1024; i += 256) ((float4*)ws4)[i] = W4[i];
    int r0 = blockIdx.x * 16;
    int rr = t >> 4, c4 = t & 15;
    if (r0 + rr < n)
        ((float4*)xs)[t] = ((const float4*)in)[(size_t)(r0 + rr) * 16 + c4];
    __syncthreads();
    if (r0 + rr < n) {
        float4 acc = {0.f, 0.f, 0.f, 0.f};
#pragma unroll
        for (int k = 0; k < 64; ++k) {
            float xv = xs[rr][k];
            float4 wv = ws4[k][c4];
            acc.x = fmaf(xv, wv.x, acc.x);
            acc.y = fmaf(xv, wv.y, acc.y);
            acc.z = fmaf(xv, wv.z, acc.z);
            acc.w = fmaf(xv, wv.w, acc.w);
        }
        ((float4*)out)[(size_t)(r0 + rr) * 16 + c4] = acc;
    }
}

// Layer-1 aggregation: wave/row, lane = feature, x4 unroll (4 gathers in
// flight). w_e = dinv[r]*attr_e*dinv[c_e] computed in-loop.
__global__ __launch_bounds__(256) void k_aggA(const float* __restrict__ src,
                                              const int* __restrict__ meta,
                                              const float* __restrict__ dinv,
                                              const int2* __restrict__ adj,
                                              const float* __restrict__ b,
                                              float* __restrict__ out, int n) {
    int r = blockIdx.x * 4 + (threadIdx.x >> 6);
    int lane = threadIdx.x & 63;
    if (r >= n) return;
    int m = meta[r];
    int len = m & 255;
    float dr = dinv[r];
    const int2* ep = adj + (m >> 8);
    float a0 = 0.f, a1 = 0.f, a2 = 0.f, a3 = 0.f;
    int nr = len >> 2;
    for (int t = 0; t < nr; ++t) {
        int2 m0 = ep[4 * t + 0];
        int2 m1 = ep[4 * t + 1];
        int2 m2 = ep[4 * t + 2];
        int2 m3 = ep[4 * t + 3];
        float w0 = dr * __int_as_float(m0.y) * dinv[m0.x];
        float w1 = dr * __int_as_float(m1.y) * dinv[m1.x];
        float w2 = dr * __int_as_float(m2.y) * dinv[m2.x];
        float w3 = dr * __int_as_float(m3.y) * dinv[m3.x];
        a0 = fmaf(w0, src[((size_t)m0.x << 6) | lane], a0);
        a1 = fmaf(w1, src[((size_t)m1.x << 6) | lane], a1);
        a2 = fmaf(w2, src[((size_t)m2.x << 6) | lane], a2);
        a3 = fmaf(w3, src[((size_t)m3.x << 6) | lane], a3);
    }
    for (int j = nr * 4; j < len; ++j) {
        int2 mm = ep[j];
        float w = dr * __int_as_float(mm.y) * dinv[mm.x];
        a0 = fmaf(w, src[((size_t)mm.x << 6) | lane], a0);
    }
    float acc = (a0 + a1) + (a2 + a3);
    float v = acc + dr * dr * src[((size_t)r << 6) | lane] + b[lane];
    out[((size_t)r << 6) | lane] = v > 0.0f ? v : 0.0f;
}

// Layer-2 aggregation fused with mean-pool (h2 never materialized).
__global__ __launch_bounds__(256) void k_aggB(const float* __restrict__ src,
                                              const int* __restrict__ meta,
                                              const float* __restrict__ dinv,
                                              const int2* __restrict__ adj,
                                              const float* __restrict__ b,
                                              float* __restrict__ pool, int n) {
    __shared__ float part[4][64];
    int wv = threadIdx.x >> 6, lane = threadIdx.x & 63;
    float pacc = 0.0f;
    for (int r = blockIdx.x * 4 + wv; r < n; r += gridDim.x * 4) {
        int m = meta[r];
        int len = m & 255;
        float dr = dinv[r];
        const int2* ep = adj + (m >> 8);
        float a0 = 0.f, a1 = 0.f, a2 = 0.f, a3 = 0.f;
        int nr = len >> 2;
        for (int t = 0; t < nr; ++t) {
            int2 m0 = ep[4 * t + 0];
            int2 m1 = ep[4 * t + 1];
            int2 m2 = ep[4 * t + 2];
            int2 m3 = ep[4 * t + 3];
            float w0 = dr * __int_as_float(m0.y) * dinv[m0.x];
            float w1 = dr * __int_as_float(m1.y) * dinv[m1.x];
            float w2 = dr * __int_as_float(m2.y) * dinv[m2.x];
            float w3 = dr * __int_as_float(m3.y) * dinv[m3.x];
            a0 = fmaf(w0, src[((size_t)m0.x << 6) | lane], a0);
            a1 = fmaf(w1, src[((size_t)m1.x << 6) | lane], a1);
            a2 = fmaf(w2, src[((size_t)m2.x << 6) | lane], a2);
            a3 = fmaf(w3, src[((size_t)m3.x << 6) | lane], a3);
        }
        for (int j = nr * 4; j < len; ++j) {
            int2 mm = ep[j];
            float w = dr * __int_as_float(mm.y) * dinv[mm.x];
            a0 = fmaf(w, src[((size_t)mm.x << 6) | lane], a0);
        }
        float acc = (a0 + a1) + (a2 + a3);
        float v = acc + dr * dr * src[((size_t)r << 6) | lane] + b[lane];
        pacc += v > 0.0f ? v : 0.0f;
    }
    part[wv][lane] = pacc;
    __syncthreads();
    if (wv == 0) {
        float s = part[0][lane] + part[1][lane] + part[2][lane] + part[3][lane];
        atomicAdd(&pool[lane], s);
    }
}

// z = [pool/N, h_other]; out = relu(z @ Wc1 + bc1) @ Wc2 + bc2
__global__ __launch_bounds__(128) void k_head(const float* __restrict__ pool,
                                              const float* __restrict__ h_other,
                                              const float* __restrict__ Wc1,
                                              const float* __restrict__ bc1,
                                              const float* __restrict__ Wc2,
                                              const float* __restrict__ bc2,
                                              float* __restrict__ out, float invN) {
    __shared__ float z[128];
    __shared__ float hid[64];
    int t = threadIdx.x;
    z[t] = (t < 64) ? pool[t] * invN : h_other[t - 64];
    __syncthreads();
    if (t < 64) {
        float acc = bc1[t];
#pragma unroll
        for (int k = 0; k < 128; ++k) acc += z[k] * Wc1[k * 64 + t];
        hid[t] = acc > 0.0f ? acc : 0.0f;
    }
    __syncthreads();
    if (t < 3) {
        float acc = bc2[t];
#pragma unroll
        for (int j = 0; j < 64; ++j) acc += hid[j] * Wc2[j * 3 + t];
        out[t] = acc;
    }
}

extern "C" void kernel_launch(void* const* d_in, const int* in_sizes, int n_in,
                              void* d_out, int out_size, void* d_ws, size_t ws_size,
                              hipStream_t stream) {
    const float* x       = (const float*)d_in[0];
    const int*   ei      = (const int*)d_in[1];
    const float* attr    = (const float*)d_in[2];
    const float* W1      = (const float*)d_in[4];
    const float* b1      = (const float*)d_in[5];
    const float* W2      = (const float*)d_in[6];
    const float* b2      = (const float*)d_in[7];
    const float* Wc1     = (const float*)d_in[8];
    const float* bc1     = (const float*)d_in[9];
    const float* Wc2     = (const float*)d_in[10];
    const float* bc2     = (const float*)d_in[11];
    const float* h_other = (const float*)d_in[12];
    float* out = (float*)d_out;

    const int N = in_sizes[3];
    const int E = in_sizes[2];
    const size_t NH = (size_t)N * 64;
    const int P = (N + PRWS - 1) >> PSHIFT;   // partitions

    // workspace (floats unless noted):
    //  buf0[NH] | buf1[NH] | dinv[N] | pool[64] | meta[N int] | pfill[P*PFS int]
    //  | pad-to-even | region[P*PCAP u64] | adj[P*PCAP int2]
    float* ws0  = (float*)d_ws;
    float* buf0 = ws0;
    float* buf1 = buf0 + NH;
    float* dinv = buf1 + NH;
    float* pool = dinv + N;
    int*   meta = (int*)(pool + 64);
    int*   pfill = meta + N;
    size_t ofs = (size_t)(2 * NH) + N + 64 + N + (size_t)P * PFS;
    ofs = (ofs + 1) & ~(size_t)1;             // 8B align
    unsigned long long* region = (unsigned long long*)(ws0 + ofs);
    int2* adj = (int2*)(region + (size_t)P * PCAP);

    const int* rows = ei;
    const int* cols = ei + E;

    // zero pool + pfill (contiguous with meta between? meta is overwritten
    // fully by k_build, no zero needed; zero pool then pfill separately-safe:
    // they are contiguous: pool(64) meta(N) pfill(P*PFS) -> two memsets)
    hipMemsetAsync(pool, 0, 64 * sizeof(float), stream);
    hipMemsetAsync(pfill, 0, (size_t)P * PFS * sizeof(int), stream);

    // --- adjacency build ---
    k_part<<<(E + 4095) / 4096, 1024, 0, stream>>>(rows, cols, attr, pfill, region, E);
    k_build<<<P, 1024, 0, stream>>>(region, pfill, adj, dinv, meta, N);

    // --- layer 1 ---
    k_gemm64<<<(N + 15) / 16, 256, 0, stream>>>(x, W1, buf0, N);
    k_aggA<<<(N + 3) / 4, 256, 0, stream>>>(buf0, meta, dinv, adj, b1, buf1, N);

    // --- layer 2 (agg fused with mean-pool) ---
    k_gemm64<<<(N + 15) / 16, 256, 0, stream>>>(buf1, W2, buf0, N);
    k_aggB<<<2048, 256, 0, stream>>>(buf0, meta, dinv, adj, b2, pool, N);

    // --- head ---
    k_head<<<1, 128, 0, stream>>>(pool, h_other, Wc1, bc1, Wc2, bc2, out,
                                  1.0f / (float)N);
}

// Round 6
// 338.496 us; speedup vs baseline: 3.0743x; 1.0450x over previous
//
#include <hip/hip_runtime.h>
#include <hip/hip_bf16.h>
#include <hip/hip_fp16.h>

// ---------------------------------------------------------------------------
// GCN pipeline, adjacency built via two-pass partitioned counting sort:
//   k_part : edges -> row-partitions (LDS ranks, ONE global atomic per
//            block-partition)
//   k_build: per-partition LDS sort -> contiguous CSR adj[] + meta + dinv
//   GEMM1 -> aggCSR1(+selfloop+bias+relu) -> GEMM2 -> aggCSR2(+pool) -> head
// H = F = 64 (== wave width). Agg: wave/row, x4-unrolled gathers.
// R6: agg src operand stored fp16 (GEMM epilogue converts) — R5 counters
// showed aggs are gather-line-throughput bound (256B/gather = 4 lines,
// 25.6MB operand >> 4MB L2/XCD). fp16 halves lines/gather and doubles the
// L2-resident fraction. Accumulation stays fp32.
// ---------------------------------------------------------------------------

#define PSHIFT 9
#define PRWS   512           // rows per partition
#define PCAP   10240         // slots per partition (mean 8192, +22 sigma)
#define PFS    16            // pfill stride (ints) = one 64B line per counter
#define VT     4             // edges per thread in k_part

// Pass 1: partition edges. Block = 1024 thr x 4 edges. LDS histogram over
// partitions -> per-edge local rank; one global atomicAdd per (block,part).
__global__ __launch_bounds__(1024) void k_part(const int* __restrict__ rows,
                                               const int* __restrict__ cols,
                                               const float* __restrict__ attr,
                                               int* __restrict__ pfill,
                                               unsigned long long* __restrict__ region,
                                               int E) {
    __shared__ int cntS[256];
    __shared__ int baseS[256];
    int t = threadIdx.x;
    if (t < 256) cntS[t] = 0;
    __syncthreads();
    int e0 = blockIdx.x * (1024 * VT);
    int pa[VT], ra[VT];
    unsigned long long rec[VT];
#pragma unroll
    for (int i = 0; i < VT; ++i) {
        int e = e0 + i * 1024 + t;
        if (e < E) {
            int r = rows[e];
            int p = r >> PSHIFT;
            pa[i]  = p;
            rec[i] = ((unsigned long long)__float_as_uint(attr[e]) << 32) |
                     ((unsigned)(r & (PRWS - 1)) << 17) | (unsigned)cols[e];
            ra[i]  = atomicAdd(&cntS[p], 1);            // LDS atomic
        } else pa[i] = -1;
    }
    __syncthreads();
    if (t < 256 && cntS[t] > 0)
        baseS[t] = atomicAdd(&pfill[t * PFS], cntS[t]); // one global atomic
    __syncthreads();
#pragma unroll
    for (int i = 0; i < VT; ++i) {
        if (pa[i] >= 0) {
            int pos = baseS[pa[i]] + ra[i];
            if (pos < PCAP)
                region[(size_t)pa[i] * PCAP + pos] = rec[i];
        }
    }
}

// Pass 2: one block per partition. LDS row-histogram + attr sums -> scan ->
// coalesced CSR placement into adj[]; also emits dinv and meta=(start<<8)|cnt.
__global__ __launch_bounds__(1024) void k_build(unsigned long long* __restrict__ region,
                                                const int* __restrict__ pfill,
                                                int2* __restrict__ adj,
                                                float* __restrict__ dinv,
                                                int* __restrict__ meta, int N) {
    __shared__ int   cntS[PRWS];
    __shared__ int   c2S[PRWS];
    __shared__ float asum[PRWS];
    __shared__ int   scan[PRWS];
    int p = blockIdx.x, t = threadIdx.x;
    int len = min(pfill[p * PFS], PCAP);
    if (t < PRWS) { cntS[t] = 0; c2S[t] = 0; asum[t] = 0.0f; }
    __syncthreads();
    const unsigned long long* base = region + (size_t)p * PCAP;
    for (int j = t; j < len; j += 1024) {
        unsigned long long v = base[j];
        int rl = (int)((v >> 17) & (PRWS - 1));
        atomicAdd(&cntS[rl], 1);
        atomicAdd(&asum[rl], __uint_as_float((unsigned)(v >> 32)));
    }
    __syncthreads();
    if (t < PRWS) scan[t] = cntS[t];
    __syncthreads();
    for (int off = 1; off < PRWS; off <<= 1) {
        int v = 0;
        if (t < PRWS && t >= off) v = scan[t - off];
        __syncthreads();
        if (t < PRWS) scan[t] += v;
        __syncthreads();
    }
    int r0 = p * PRWS;
    if (t < PRWS) {
        int r = r0 + t;
        if (r < N) {
            int start = p * PCAP + (scan[t] - cntS[t]);   // exclusive offset
            meta[r] = (start << 8) | min(cntS[t], 255);
            dinv[r] = rsqrtf(1.0f + asum[t]);
        }
    }
    __syncthreads();
    for (int j = t; j < len; j += 1024) {
        unsigned long long v = base[j];
        int rl   = (int)((v >> 17) & (PRWS - 1));
        int rank = atomicAdd(&c2S[rl], 1);
        int dst  = p * PCAP + (scan[rl] - cntS[rl]) + rank;
        adj[dst] = make_int2((int)(v & 0x1FFFF), (int)(v >> 32));
    }
}

// out[n x 64] (fp16) = in[n x 64] (fp32) @ W[64 x 64]; 16 rows/block,
// thread = 1 row x 4 cols; epilogue converts to __half2 pairs.
__global__ __launch_bounds__(256) void k_gemm64(const float* __restrict__ in,
                                                const float* __restrict__ W,
                                                __half* __restrict__ out, int n) {
    __shared__ float4 ws4[64][16];
    __shared__ float xs[16][64];
    int t = threadIdx.x;
    const float4* W4 = (const float4*)W;
    for (int i = t; i < 1024; i += 256) ((float4*)ws4)[i] = W4[i];
    int r0 = blockIdx.x * 16;
    int rr = t >> 4, c4 = t & 15;
    if (r0 + rr < n)
        ((float4*)xs)[t] = ((const float4*)in)[(size_t)(r0 + rr) * 16 + c4];
    __syncthreads();
    if (r0 + rr < n) {
        float4 acc = {0.f, 0.f, 0.f, 0.f};
#pragma unroll
        for (int k = 0; k < 64; ++k) {
            float xv = xs[rr][k];
            float4 wv = ws4[k][c4];
            acc.x = fmaf(xv, wv.x, acc.x);
            acc.y = fmaf(xv, wv.y, acc.y);
            acc.z = fmaf(xv, wv.z, acc.z);
            acc.w = fmaf(xv, wv.w, acc.w);
        }
        __half2* o2 = (__half2*)out;
        size_t ob = (size_t)(r0 + rr) * 32 + c4 * 2;
        o2[ob + 0] = __floats2half2_rn(acc.x, acc.y);
        o2[ob + 1] = __floats2half2_rn(acc.z, acc.w);
    }
}

// Layer-1 aggregation: wave/row, lane = feature, x4 unroll (4 gathers in
// flight, 128B each). w_e = dinv[r]*attr_e*dinv[c_e] computed in-loop.
__global__ __launch_bounds__(256) void k_aggA(const __half* __restrict__ src,
                                              const int* __restrict__ meta,
                                              const float* __restrict__ dinv,
                                              const int2* __restrict__ adj,
                                              const float* __restrict__ b,
                                              float* __restrict__ out, int n) {
    int r = blockIdx.x * 4 + (threadIdx.x >> 6);
    int lane = threadIdx.x & 63;
    if (r >= n) return;
    int m = meta[r];
    int len = m & 255;
    float dr = dinv[r];
    const int2* ep = adj + (m >> 8);
    float a0 = 0.f, a1 = 0.f, a2 = 0.f, a3 = 0.f;
    int nr = len >> 2;
    for (int t = 0; t < nr; ++t) {
        int2 m0 = ep[4 * t + 0];
        int2 m1 = ep[4 * t + 1];
        int2 m2 = ep[4 * t + 2];
        int2 m3 = ep[4 * t + 3];
        float s0 = __half2float(src[((size_t)m0.x << 6) | lane]);
        float s1 = __half2float(src[((size_t)m1.x << 6) | lane]);
        float s2 = __half2float(src[((size_t)m2.x << 6) | lane]);
        float s3 = __half2float(src[((size_t)m3.x << 6) | lane]);
        float w0 = dr * __int_as_float(m0.y) * dinv[m0.x];
        float w1 = dr * __int_as_float(m1.y) * dinv[m1.x];
        float w2 = dr * __int_as_float(m2.y) * dinv[m2.x];
        float w3 = dr * __int_as_float(m3.y) * dinv[m3.x];
        a0 = fmaf(w0, s0, a0);
        a1 = fmaf(w1, s1, a1);
        a2 = fmaf(w2, s2, a2);
        a3 = fmaf(w3, s3, a3);
    }
    for (int j = nr * 4; j < len; ++j) {
        int2 mm = ep[j];
        float w = dr * __int_as_float(mm.y) * dinv[mm.x];
        a0 = fmaf(w, __half2float(src[((size_t)mm.x << 6) | lane]), a0);
    }
    float acc = (a0 + a1) + (a2 + a3);
    float v = acc + dr * dr * __half2float(src[((size_t)r << 6) | lane]) + b[lane];
    out[((size_t)r << 6) | lane] = v > 0.0f ? v : 0.0f;
}

// Layer-2 aggregation fused with mean-pool (h2 never materialized).
__global__ __launch_bounds__(256) void k_aggB(const __half* __restrict__ src,
                                              const int* __restrict__ meta,
                                              const float* __restrict__ dinv,
                                              const int2* __restrict__ adj,
                                              const float* __restrict__ b,
                                              float* __restrict__ pool, int n) {
    __shared__ float part[4][64];
    int wv = threadIdx.x >> 6, lane = threadIdx.x & 63;
    float pacc = 0.0f;
    for (int r = blockIdx.x * 4 + wv; r < n; r += gridDim.x * 4) {
        int m = meta[r];
        int len = m & 255;
        float dr = dinv[r];
        const int2* ep = adj + (m >> 8);
        float a0 = 0.f, a1 = 0.f, a2 = 0.f, a3 = 0.f;
        int nr = len >> 2;
        for (int t = 0; t < nr; ++t) {
            int2 m0 = ep[4 * t + 0];
            int2 m1 = ep[4 * t + 1];
            int2 m2 = ep[4 * t + 2];
            int2 m3 = ep[4 * t + 3];
            float s0 = __half2float(src[((size_t)m0.x << 6) | lane]);
            float s1 = __half2float(src[((size_t)m1.x << 6) | lane]);
            float s2 = __half2float(src[((size_t)m2.x << 6) | lane]);
            float s3 = __half2float(src[((size_t)m3.x << 6) | lane]);
            float w0 = dr * __int_as_float(m0.y) * dinv[m0.x];
            float w1 = dr * __int_as_float(m1.y) * dinv[m1.x];
            float w2 = dr * __int_as_float(m2.y) * dinv[m2.x];
            float w3 = dr * __int_as_float(m3.y) * dinv[m3.x];
            a0 = fmaf(w0, s0, a0);
            a1 = fmaf(w1, s1, a1);
            a2 = fmaf(w2, s2, a2);
            a3 = fmaf(w3, s3, a3);
        }
        for (int j = nr * 4; j < len; ++j) {
            int2 mm = ep[j];
            float w = dr * __int_as_float(mm.y) * dinv[mm.x];
            a0 = fmaf(w, __half2float(src[((size_t)mm.x << 6) | lane]), a0);
        }
        float acc = (a0 + a1) + (a2 + a3);
        float v = acc + dr * dr * __half2float(src[((size_t)r << 6) | lane]) + b[lane];
        pacc += v > 0.0f ? v : 0.0f;
    }
    part[wv][lane] = pacc;
    __syncthreads();
    if (wv == 0) {
        float s = part[0][lane] + part[1][lane] + part[2][lane] + part[3][lane];
        atomicAdd(&pool[lane], s);
    }
}

// z = [pool/N, h_other]; out = relu(z @ Wc1 + bc1) @ Wc2 + bc2
__global__ __launch_bounds__(128) void k_head(const float* __restrict__ pool,
                                              const float* __restrict__ h_other,
                                              const float* __restrict__ Wc1,
                                              const float* __restrict__ bc1,
                                              const float* __restrict__ Wc2,
                                              const float* __restrict__ bc2,
                                              float* __restrict__ out, float invN) {
    __shared__ float z[128];
    __shared__ float hid[64];
    int t = threadIdx.x;
    z[t] = (t < 64) ? pool[t] * invN : h_other[t - 64];
    __syncthreads();
    if (t < 64) {
        float acc = bc1[t];
#pragma unroll
        for (int k = 0; k < 128; ++k) acc += z[k] * Wc1[k * 64 + t];
        hid[t] = acc > 0.0f ? acc : 0.0f;
    }
    __syncthreads();
    if (t < 3) {
        float acc = bc2[t];
#pragma unroll
        for (int j = 0; j < 64; ++j) acc += hid[j] * Wc2[j * 3 + t];
        out[t] = acc;
    }
}

extern "C" void kernel_launch(void* const* d_in, const int* in_sizes, int n_in,
                              void* d_out, int out_size, void* d_ws, size_t ws_size,
                              hipStream_t stream) {
    const float* x       = (const float*)d_in[0];
    const int*   ei      = (const int*)d_in[1];
    const float* attr    = (const float*)d_in[2];
    const float* W1      = (const float*)d_in[4];
    const float* b1      = (const float*)d_in[5];
    const float* W2      = (const float*)d_in[6];
    const float* b2      = (const float*)d_in[7];
    const float* Wc1     = (const float*)d_in[8];
    const float* bc1     = (const float*)d_in[9];
    const float* Wc2     = (const float*)d_in[10];
    const float* bc2     = (const float*)d_in[11];
    const float* h_other = (const float*)d_in[12];
    float* out = (float*)d_out;

    const int N = in_sizes[3];
    const int E = in_sizes[2];
    const size_t NH = (size_t)N * 64;
    const int P = (N + PRWS - 1) >> PSHIFT;   // partitions

    // workspace (float units; buf0 only uses half its span now — fp16):
    //  buf0[NH] | buf1[NH] | dinv[N] | pool[64] | meta[N int] | pfill[P*PFS int]
    //  | pad-to-even | region[P*PCAP u64] | adj[P*PCAP int2]
    float* ws0  = (float*)d_ws;
    __half* buf0 = (__half*)ws0;              // NH halves (uses NH/2 floats)
    float* buf1 = ws0 + NH;
    float* dinv = buf1 + NH;
    float* pool = dinv + N;
    int*   meta = (int*)(pool + 64);
    int*   pfill = meta + N;
    size_t ofs = (size_t)(2 * NH) + N + 64 + N + (size_t)P * PFS;
    ofs = (ofs + 1) & ~(size_t)1;             // 8B align
    unsigned long long* region = (unsigned long long*)(ws0 + ofs);
    int2* adj = (int2*)(region + (size_t)P * PCAP);

    const int* rows = ei;
    const int* cols = ei + E;

    hipMemsetAsync(pool, 0, 64 * sizeof(float), stream);
    hipMemsetAsync(pfill, 0, (size_t)P * PFS * sizeof(int), stream);

    // --- adjacency build ---
    k_part<<<(E + 4095) / 4096, 1024, 0, stream>>>(rows, cols, attr, pfill, region, E);
    k_build<<<P, 1024, 0, stream>>>(region, pfill, adj, dinv, meta, N);

    // --- layer 1 ---
    k_gemm64<<<(N + 15) / 16, 256, 0, stream>>>(x, W1, buf0, N);
    k_aggA<<<(N + 3) / 4, 256, 0, stream>>>(buf0, meta, dinv, adj, b1, buf1, N);

    // --- layer 2 (agg fused with mean-pool) ---
    k_gemm64<<<(N + 15) / 16, 256, 0, stream>>>(buf1, W2, buf0, N);
    k_aggB<<<2048, 256, 0, stream>>>(buf0, meta, dinv, adj, b2, pool, N);

    // --- head ---
    k_head<<<1, 128, 0, stream>>>(pool, h_other, Wc1, bc1, Wc2, bc2, out,
                                  1.0f / (float)N);
}

// Round 7
// 314.254 us; speedup vs baseline: 3.3114x; 1.0771x over previous
//
#include <hip/hip_runtime.h>
#include <hip/hip_bf16.h>
#include <hip/hip_fp16.h>

// ---------------------------------------------------------------------------
// GCN pipeline. R6 post-mortem: aggs are latency*concurrency bound on VMEM
// REQUEST COUNT (fp16 halved FETCH_SIZE but time -7%). R7:
//  (1) dinv folded into GEMM epilogue (src' = dinv[c]*XW[c]) -> no per-edge
//      dinv gather:  h[r] = relu(dr*(sum attr_e*src'[c_e] + src'[r]) + b)
//  (2) CSR row starts even-aligned -> edge PAIRS loaded as one int4
//  (3) edge loop unrolled x8 (8 independent gathers in flight)
// Requests/edge ~5 -> ~2.5; outstanding/wave ~6 -> ~10.
// ---------------------------------------------------------------------------

#define PSHIFT 9
#define PRWS   512           // rows per partition
#define PCAP   10240         // slots per partition (mean 8192 + pad + slack)
#define PFS    16            // pfill stride (ints) = one 64B line per counter
#define VT     4             // edges per thread in k_part

// Pass 1: partition edges. LDS ranks; one global atomic per (block,part).
__global__ __launch_bounds__(1024) void k_part(const int* __restrict__ rows,
                                               const int* __restrict__ cols,
                                               const float* __restrict__ attr,
                                               int* __restrict__ pfill,
                                               unsigned long long* __restrict__ region,
                                               int E) {
    __shared__ int cntS[256];
    __shared__ int baseS[256];
    int t = threadIdx.x;
    if (t < 256) cntS[t] = 0;
    __syncthreads();
    int e0 = blockIdx.x * (1024 * VT);
    int pa[VT], ra[VT];
    unsigned long long rec[VT];
#pragma unroll
    for (int i = 0; i < VT; ++i) {
        int e = e0 + i * 1024 + t;
        if (e < E) {
            int r = rows[e];
            int p = r >> PSHIFT;
            pa[i]  = p;
            rec[i] = ((unsigned long long)__float_as_uint(attr[e]) << 32) |
                     ((unsigned)(r & (PRWS - 1)) << 17) | (unsigned)cols[e];
            ra[i]  = atomicAdd(&cntS[p], 1);            // LDS atomic
        } else pa[i] = -1;
    }
    __syncthreads();
    if (t < 256 && cntS[t] > 0)
        baseS[t] = atomicAdd(&pfill[t * PFS], cntS[t]); // one global atomic
    __syncthreads();
#pragma unroll
    for (int i = 0; i < VT; ++i) {
        if (pa[i] >= 0) {
            int pos = baseS[pa[i]] + ra[i];
            if (pos < PCAP)
                region[(size_t)pa[i] * PCAP + pos] = rec[i];
        }
    }
}

// Pass 2: one block per partition. Row starts padded to EVEN (int4-aligned
// pairs for the agg loop). Emits adj, dinv, meta=(start<<8)|cnt.
__global__ __launch_bounds__(1024) void k_build(unsigned long long* __restrict__ region,
                                                const int* __restrict__ pfill,
                                                int2* __restrict__ adj,
                                                float* __restrict__ dinv,
                                                int* __restrict__ meta, int N) {
    __shared__ int   cntS[PRWS];
    __shared__ int   c2S[PRWS];
    __shared__ float asum[PRWS];
    __shared__ int   scan[PRWS];
    __shared__ int   startS[PRWS];
    int p = blockIdx.x, t = threadIdx.x;
    int len = min(pfill[p * PFS], PCAP);
    if (t < PRWS) { cntS[t] = 0; c2S[t] = 0; asum[t] = 0.0f; }
    __syncthreads();
    const unsigned long long* base = region + (size_t)p * PCAP;
    for (int j = t; j < len; j += 1024) {
        unsigned long long v = base[j];
        int rl = (int)((v >> 17) & (PRWS - 1));
        atomicAdd(&cntS[rl], 1);
        atomicAdd(&asum[rl], __uint_as_float((unsigned)(v >> 32)));
    }
    __syncthreads();
    // inclusive scan over even-padded counts
    if (t < PRWS) scan[t] = (cntS[t] + 1) & ~1;
    __syncthreads();
    for (int off = 1; off < PRWS; off <<= 1) {
        int v = 0;
        if (t < PRWS && t >= off) v = scan[t - off];
        __syncthreads();
        if (t < PRWS) scan[t] += v;
        __syncthreads();
    }
    int r0 = p * PRWS;
    if (t < PRWS) {
        int pad = (cntS[t] + 1) & ~1;
        int start = p * PCAP + (scan[t] - pad);          // even offset
        startS[t] = start;
        int r = r0 + t;
        if (r < N) {
            meta[r] = (start << 8) | min(cntS[t], 255);
            dinv[r] = rsqrtf(1.0f + asum[t]);
        }
    }
    __syncthreads();
    for (int j = t; j < len; j += 1024) {
        unsigned long long v = base[j];
        int rl   = (int)((v >> 17) & (PRWS - 1));
        int rank = atomicAdd(&c2S[rl], 1);
        adj[startS[rl] + rank] = make_int2((int)(v & 0x1FFFF), (int)(v >> 32));
    }
}

// out[n x 64] (fp16) = dscale[r] * (in[n x 64] @ W[64 x 64]); 16 rows/block,
// thread = 1 row x 4 cols.
__global__ __launch_bounds__(256) void k_gemm64(const float* __restrict__ in,
                                                const float* __restrict__ W,
                                                const float* __restrict__ dscale,
                                                __half* __restrict__ out, int n) {
    __shared__ float4 ws4[64][16];
    __shared__ float xs[16][64];
    int t = threadIdx.x;
    const float4* W4 = (const float4*)W;
    for (int i = t; i < 1024; i += 256) ((float4*)ws4)[i] = W4[i];
    int r0 = blockIdx.x * 16;
    int rr = t >> 4, c4 = t & 15;
    if (r0 + rr < n)
        ((float4*)xs)[t] = ((const float4*)in)[(size_t)(r0 + rr) * 16 + c4];
    __syncthreads();
    if (r0 + rr < n) {
        float4 acc = {0.f, 0.f, 0.f, 0.f};
#pragma unroll
        for (int k = 0; k < 64; ++k) {
            float xv = xs[rr][k];
            float4 wv = ws4[k][c4];
            acc.x = fmaf(xv, wv.x, acc.x);
            acc.y = fmaf(xv, wv.y, acc.y);
            acc.z = fmaf(xv, wv.z, acc.z);
            acc.w = fmaf(xv, wv.w, acc.w);
        }
        float ds = dscale[r0 + rr];
        __half2* o2 = (__half2*)out;
        size_t ob = (size_t)(r0 + rr) * 32 + c4 * 2;
        o2[ob + 0] = __floats2half2_rn(acc.x * ds, acc.y * ds);
        o2[ob + 1] = __floats2half2_rn(acc.z * ds, acc.w * ds);
    }
}

#define GATHER(c) __half2float(src[((size_t)(c) << 6) | lane])

// Layer-1 aggregation: wave/row, lane = feature. int4 edge-pair loads,
// x8 unroll. h[r] = relu(dr*(sum attr_e*src'[c_e] + src'[r]) + b)
__global__ __launch_bounds__(256) void k_aggA(const __half* __restrict__ src,
                                              const int* __restrict__ meta,
                                              const float* __restrict__ dinv,
                                              const int2* __restrict__ adj,
                                              const float* __restrict__ b,
                                              float* __restrict__ out, int n) {
    int r = blockIdx.x * 4 + (threadIdx.x >> 6);
    int lane = threadIdx.x & 63;
    if (r >= n) return;
    int m = meta[r];
    int len = m & 255;
    float dr = dinv[r];
    const int2* ep = adj + (m >> 8);
    const int4* ep4 = (const int4*)ep;      // start is even -> 16B aligned
    float a0 = 0.f, a1 = 0.f, a2 = 0.f, a3 = 0.f;
    float a4 = 0.f, a5 = 0.f, a6 = 0.f, a7 = 0.f;
    int npair = len >> 1;
    int nq = npair >> 2;                    // 8 edges per iter
    for (int t = 0; t < nq; ++t) {
        int4 p0 = ep4[4 * t + 0];
        int4 p1 = ep4[4 * t + 1];
        int4 p2 = ep4[4 * t + 2];
        int4 p3 = ep4[4 * t + 3];
        a0 = fmaf(__int_as_float(p0.y), GATHER(p0.x), a0);
        a1 = fmaf(__int_as_float(p0.w), GATHER(p0.z), a1);
        a2 = fmaf(__int_as_float(p1.y), GATHER(p1.x), a2);
        a3 = fmaf(__int_as_float(p1.w), GATHER(p1.z), a3);
        a4 = fmaf(__int_as_float(p2.y), GATHER(p2.x), a4);
        a5 = fmaf(__int_as_float(p2.w), GATHER(p2.z), a5);
        a6 = fmaf(__int_as_float(p3.y), GATHER(p3.x), a6);
        a7 = fmaf(__int_as_float(p3.w), GATHER(p3.z), a7);
    }
    for (int j = nq * 4; j < npair; ++j) {  // leftover pairs
        int4 p = ep4[j];
        a0 = fmaf(__int_as_float(p.y), GATHER(p.x), a0);
        a1 = fmaf(__int_as_float(p.w), GATHER(p.z), a1);
    }
    if (len & 1) {                          // odd tail edge
        int2 mm = ep[len - 1];
        a2 = fmaf(__int_as_float(mm.y), GATHER(mm.x), a2);
    }
    float acc = ((a0 + a1) + (a2 + a3)) + ((a4 + a5) + (a6 + a7));
    float v = dr * (acc + GATHER(r)) + b[lane];
    out[((size_t)r << 6) | lane] = v > 0.0f ? v : 0.0f;
}

// Layer-2 aggregation fused with mean-pool (h2 never materialized).
__global__ __launch_bounds__(256) void k_aggB(const __half* __restrict__ src,
                                              const int* __restrict__ meta,
                                              const float* __restrict__ dinv,
                                              const int2* __restrict__ adj,
                                              const float* __restrict__ b,
                                              float* __restrict__ pool, int n) {
    __shared__ float part[4][64];
    int wv = threadIdx.x >> 6, lane = threadIdx.x & 63;
    float pacc = 0.0f;
    for (int r = blockIdx.x * 4 + wv; r < n; r += gridDim.x * 4) {
        int m = meta[r];
        int len = m & 255;
        float dr = dinv[r];
        const int2* ep = adj + (m >> 8);
        const int4* ep4 = (const int4*)ep;
        float a0 = 0.f, a1 = 0.f, a2 = 0.f, a3 = 0.f;
        float a4 = 0.f, a5 = 0.f, a6 = 0.f, a7 = 0.f;
        int npair = len >> 1;
        int nq = npair >> 2;
        for (int t = 0; t < nq; ++t) {
            int4 p0 = ep4[4 * t + 0];
            int4 p1 = ep4[4 * t + 1];
            int4 p2 = ep4[4 * t + 2];
            int4 p3 = ep4[4 * t + 3];
            a0 = fmaf(__int_as_float(p0.y), GATHER(p0.x), a0);
            a1 = fmaf(__int_as_float(p0.w), GATHER(p0.z), a1);
            a2 = fmaf(__int_as_float(p1.y), GATHER(p1.x), a2);
            a3 = fmaf(__int_as_float(p1.w), GATHER(p1.z), a3);
            a4 = fmaf(__int_as_float(p2.y), GATHER(p2.x), a4);
            a5 = fmaf(__int_as_float(p2.w), GATHER(p2.z), a5);
            a6 = fmaf(__int_as_float(p3.y), GATHER(p3.x), a6);
            a7 = fmaf(__int_as_float(p3.w), GATHER(p3.z), a7);
        }
        for (int j = nq * 4; j < npair; ++j) {
            int4 p = ep4[j];
            a0 = fmaf(__int_as_float(p.y), GATHER(p.x), a0);
            a1 = fmaf(__int_as_float(p.w), GATHER(p.z), a1);
        }
        if (len & 1) {
            int2 mm = ep[len - 1];
            a2 = fmaf(__int_as_float(mm.y), GATHER(mm.x), a2);
        }
        float acc = ((a0 + a1) + (a2 + a3)) + ((a4 + a5) + (a6 + a7));
        float v = dr * (acc + GATHER(r)) + b[lane];
        pacc += v > 0.0f ? v : 0.0f;
    }
    part[wv][lane] = pacc;
    __syncthreads();
    if (wv == 0) {
        float s = part[0][lane] + part[1][lane] + part[2][lane] + part[3][lane];
        atomicAdd(&pool[lane], s);
    }
}

// z = [pool/N, h_other]; out = relu(z @ Wc1 + bc1) @ Wc2 + bc2
__global__ __launch_bounds__(128) void k_head(const float* __restrict__ pool,
                                              const float* __restrict__ h_other,
                                              const float* __restrict__ Wc1,
                                              const float* __restrict__ bc1,
                                              const float* __restrict__ Wc2,
                                              const float* __restrict__ bc2,
                                              float* __restrict__ out, float invN) {
    __shared__ float z[128];
    __shared__ float hid[64];
    int t = threadIdx.x;
    z[t] = (t < 64) ? pool[t] * invN : h_other[t - 64];
    __syncthreads();
    if (t < 64) {
        float acc = bc1[t];
#pragma unroll
        for (int k = 0; k < 128; ++k) acc += z[k] * Wc1[k * 64 + t];
        hid[t] = acc > 0.0f ? acc : 0.0f;
    }
    __syncthreads();
    if (t < 3) {
        float acc = bc2[t];
#pragma unroll
        for (int j = 0; j < 64; ++j) acc += hid[j] * Wc2[j * 3 + t];
        out[t] = acc;
    }
}

extern "C" void kernel_launch(void* const* d_in, const int* in_sizes, int n_in,
                              void* d_out, int out_size, void* d_ws, size_t ws_size,
                              hipStream_t stream) {
    const float* x       = (const float*)d_in[0];
    const int*   ei      = (const int*)d_in[1];
    const float* attr    = (const float*)d_in[2];
    const float* W1      = (const float*)d_in[4];
    const float* b1      = (const float*)d_in[5];
    const float* W2      = (const float*)d_in[6];
    const float* b2      = (const float*)d_in[7];
    const float* Wc1     = (const float*)d_in[8];
    const float* bc1     = (const float*)d_in[9];
    const float* Wc2     = (const float*)d_in[10];
    const float* bc2     = (const float*)d_in[11];
    const float* h_other = (const float*)d_in[12];
    float* out = (float*)d_out;

    const int N = in_sizes[3];
    const int E = in_sizes[2];
    const size_t NH = (size_t)N * 64;
    const int P = (N + PRWS - 1) >> PSHIFT;   // partitions

    // workspace (float units):
    //  buf0[NH(half-used, fp16)] | buf1[NH] | dinv[N] | pool[64] | meta[N int]
    //  | pfill[P*PFS int] | pad | region[P*PCAP u64] | adj[P*PCAP int2]
    float* ws0  = (float*)d_ws;
    __half* buf0 = (__half*)ws0;
    float* buf1 = ws0 + NH;
    float* dinv = buf1 + NH;
    float* pool = dinv + N;
    int*   meta = (int*)(pool + 64);
    int*   pfill = meta + N;
    size_t ofs = (size_t)(2 * NH) + N + 64 + N + (size_t)P * PFS;
    ofs = (ofs + 1) & ~(size_t)1;             // 8B align
    unsigned long long* region = (unsigned long long*)(ws0 + ofs);
    int2* adj = (int2*)(region + (size_t)P * PCAP);

    const int* rows = ei;
    const int* cols = ei + E;

    hipMemsetAsync(pool, 0, 64 * sizeof(float), stream);
    hipMemsetAsync(pfill, 0, (size_t)P * PFS * sizeof(int), stream);

    // --- adjacency build ---
    k_part<<<(E + 4095) / 4096, 1024, 0, stream>>>(rows, cols, attr, pfill, region, E);
    k_build<<<P, 1024, 0, stream>>>(region, pfill, adj, dinv, meta, N);

    // --- layer 1 (GEMM epilogue scales row r by dinv[r]) ---
    k_gemm64<<<(N + 15) / 16, 256, 0, stream>>>(x, W1, dinv, buf0, N);
    k_aggA<<<(N + 3) / 4, 256, 0, stream>>>(buf0, meta, dinv, adj, b1, buf1, N);

    // --- layer 2 (agg fused with mean-pool) ---
    k_gemm64<<<(N + 15) / 16, 256, 0, stream>>>(buf1, W2, dinv, buf0, N);
    k_aggB<<<2048, 256, 0, stream>>>(buf0, meta, dinv, adj, b2, pool, N);

    // --- head ---
    k_head<<<1, 128, 0, stream>>>(pool, h_other, Wc1, bc1, Wc2, bc2, out,
                                  1.0f / (float)N);
}

// Round 8
// 306.780 us; speedup vs baseline: 3.3921x; 1.0244x over previous
//
#include <hip/hip_runtime.h>
#include <hip/hip_bf16.h>
#include <hip/hip_fp16.h>

// ---------------------------------------------------------------------------
// GCN pipeline. R7 post-mortem: aggs sit at a ~60us floor that tracks VMEM
// *instruction* count (bytes -7%, requests -15%). R8 experiment: pack TWO
// edges per wave-gather. src stored as __half2 feature-pairs: 32 lanes x 4B
// = one 64-feature row; wave = 2 independent 32-lane halves gathering two
// different edges' rows from one int4 metadata load. Gather instrs / edge
// halve. Per-row cross-half combine via __shfl_xor(32).
// Rows are even-padded in adj with a ZEROED pad slot (w=0) -> no tail code.
// ---------------------------------------------------------------------------

#define PSHIFT 9
#define PRWS   512           // rows per partition
#define PCAP   10240         // slots per partition (8192 mean + pads + slack)
#define PFS    16            // pfill stride (ints) = one 64B line per counter
#define VT     4             // edges per thread in k_part

// Pass 1: partition edges. LDS ranks; one global atomic per (block,part).
__global__ __launch_bounds__(1024) void k_part(const int* __restrict__ rows,
                                               const int* __restrict__ cols,
                                               const float* __restrict__ attr,
                                               int* __restrict__ pfill,
                                               unsigned long long* __restrict__ region,
                                               int E) {
    __shared__ int cntS[256];
    __shared__ int baseS[256];
    int t = threadIdx.x;
    if (t < 256) cntS[t] = 0;
    __syncthreads();
    int e0 = blockIdx.x * (1024 * VT);
    int pa[VT], ra[VT];
    unsigned long long rec[VT];
#pragma unroll
    for (int i = 0; i < VT; ++i) {
        int e = e0 + i * 1024 + t;
        if (e < E) {
            int r = rows[e];
            int p = r >> PSHIFT;
            pa[i]  = p;
            rec[i] = ((unsigned long long)__float_as_uint(attr[e]) << 32) |
                     ((unsigned)(r & (PRWS - 1)) << 17) | (unsigned)cols[e];
            ra[i]  = atomicAdd(&cntS[p], 1);            // LDS atomic
        } else pa[i] = -1;
    }
    __syncthreads();
    if (t < 256 && cntS[t] > 0)
        baseS[t] = atomicAdd(&pfill[t * PFS], cntS[t]); // one global atomic
    __syncthreads();
#pragma unroll
    for (int i = 0; i < VT; ++i) {
        if (pa[i] >= 0) {
            int pos = baseS[pa[i]] + ra[i];
            if (pos < PCAP)
                region[(size_t)pa[i] * PCAP + pos] = rec[i];
        }
    }
}

// Pass 2: one block per partition. Row starts even-aligned; odd rows get a
// ZEROED pad slot (col=0, w=0). Emits adj, dinv, meta=(start<<8)|cnt.
__global__ __launch_bounds__(1024) void k_build(unsigned long long* __restrict__ region,
                                                const int* __restrict__ pfill,
                                                int2* __restrict__ adj,
                                                float* __restrict__ dinv,
                                                int* __restrict__ meta, int N) {
    __shared__ int   cntS[PRWS];
    __shared__ int   c2S[PRWS];
    __shared__ float asum[PRWS];
    __shared__ int   scan[PRWS];
    __shared__ int   startS[PRWS];
    int p = blockIdx.x, t = threadIdx.x;
    int len = min(pfill[p * PFS], PCAP);
    if (t < PRWS) { cntS[t] = 0; c2S[t] = 0; asum[t] = 0.0f; }
    __syncthreads();
    const unsigned long long* base = region + (size_t)p * PCAP;
    for (int j = t; j < len; j += 1024) {
        unsigned long long v = base[j];
        int rl = (int)((v >> 17) & (PRWS - 1));
        atomicAdd(&cntS[rl], 1);
        atomicAdd(&asum[rl], __uint_as_float((unsigned)(v >> 32)));
    }
    __syncthreads();
    if (t < PRWS) scan[t] = (cntS[t] + 1) & ~1;   // even-padded counts
    __syncthreads();
    for (int off = 1; off < PRWS; off <<= 1) {
        int v = 0;
        if (t < PRWS && t >= off) v = scan[t - off];
        __syncthreads();
        if (t < PRWS) scan[t] += v;
        __syncthreads();
    }
    int r0 = p * PRWS;
    if (t < PRWS) {
        int pad = (cntS[t] + 1) & ~1;
        int start = p * PCAP + (scan[t] - pad);   // even offset
        startS[t] = start;
        int r = r0 + t;
        if (r < N) {
            meta[r] = (start << 8) | min(cntS[t], 255);
            dinv[r] = rsqrtf(1.0f + asum[t]);
        }
        if (cntS[t] & 1) adj[start + cntS[t]] = make_int2(0, 0);  // zero pad
    }
    __syncthreads();
    for (int j = t; j < len; j += 1024) {
        unsigned long long v = base[j];
        int rl   = (int)((v >> 17) & (PRWS - 1));
        int rank = atomicAdd(&c2S[rl], 1);
        adj[startS[rl] + rank] = make_int2((int)(v & 0x1FFFF), (int)(v >> 32));
    }
}

// out[n x 64] (fp16) = dscale[r] * (in[n x 64] @ W[64 x 64]); 16 rows/block,
// thread = 1 row x 4 cols.
__global__ __launch_bounds__(256) void k_gemm64(const float* __restrict__ in,
                                                const float* __restrict__ W,
                                                const float* __restrict__ dscale,
                                                __half* __restrict__ out, int n) {
    __shared__ float4 ws4[64][16];
    __shared__ float xs[16][64];
    int t = threadIdx.x;
    const float4* W4 = (const float4*)W;
    for (int i = t; i < 1024; i += 256) ((float4*)ws4)[i] = W4[i];
    int r0 = blockIdx.x * 16;
    int rr = t >> 4, c4 = t & 15;
    if (r0 + rr < n)
        ((float4*)xs)[t] = ((const float4*)in)[(size_t)(r0 + rr) * 16 + c4];
    __syncthreads();
    if (r0 + rr < n) {
        float4 acc = {0.f, 0.f, 0.f, 0.f};
#pragma unroll
        for (int k = 0; k < 64; ++k) {
            float xv = xs[rr][k];
            float4 wv = ws4[k][c4];
            acc.x = fmaf(xv, wv.x, acc.x);
            acc.y = fmaf(xv, wv.y, acc.y);
            acc.z = fmaf(xv, wv.z, acc.z);
            acc.w = fmaf(xv, wv.w, acc.w);
        }
        float ds = dscale[r0 + rr];
        __half2* o2 = (__half2*)out;
        size_t ob = (size_t)(r0 + rr) * 32 + c4 * 2;
        o2[ob + 0] = __floats2half2_rn(acc.x * ds, acc.y * ds);
        o2[ob + 1] = __floats2half2_rn(acc.z * ds, acc.w * ds);
    }
}

// Layer-1 aggregation: one wave per row; wave = 2 half-waves of 32 lanes,
// each half gathers a DIFFERENT edge's 128B row (one instr = 2 edges).
// Lane li holds feature pair (2li, 2li+1) as half2 -> float2 accumulators.
__global__ __launch_bounds__(256) void k_aggA(const __half* __restrict__ src,
                                              const int* __restrict__ meta,
                                              const float* __restrict__ dinv,
                                              const int2* __restrict__ adj,
                                              const float* __restrict__ b,
                                              float* __restrict__ out, int n) {
    int r = blockIdx.x * 4 + (threadIdx.x >> 6);
    int lane = threadIdx.x & 63;
    if (r >= n) return;
    int li = lane & 31;
    bool hi = lane >= 32;
    const __half2* src2 = (const __half2*)src;
    int m = meta[r];
    int len = m & 255;
    float dr = dinv[r];
    const int4* ep4 = (const int4*)(adj + (m >> 8));   // start even -> 16B ok
    float a0x=0,a0y=0,a1x=0,a1y=0,a2x=0,a2y=0,a3x=0,a3y=0;
    int npair = (len + 1) >> 1;     // pad slot is zeroed -> safe
    int nq = npair >> 2;
    for (int t = 0; t < nq; ++t) {
        int4 p0 = ep4[4 * t + 0];
        int4 p1 = ep4[4 * t + 1];
        int4 p2 = ep4[4 * t + 2];
        int4 p3 = ep4[4 * t + 3];
        int   c0 = hi ? p0.z : p0.x;  float w0 = __int_as_float(hi ? p0.w : p0.y);
        int   c1 = hi ? p1.z : p1.x;  float w1 = __int_as_float(hi ? p1.w : p1.y);
        int   c2 = hi ? p2.z : p2.x;  float w2 = __int_as_float(hi ? p2.w : p2.y);
        int   c3 = hi ? p3.z : p3.x;  float w3 = __int_as_float(hi ? p3.w : p3.y);
        float2 s0 = __half22float2(src2[((size_t)c0 << 5) + li]);
        float2 s1 = __half22float2(src2[((size_t)c1 << 5) + li]);
        float2 s2 = __half22float2(src2[((size_t)c2 << 5) + li]);
        float2 s3 = __half22float2(src2[((size_t)c3 << 5) + li]);
        a0x = fmaf(w0, s0.x, a0x);  a0y = fmaf(w0, s0.y, a0y);
        a1x = fmaf(w1, s1.x, a1x);  a1y = fmaf(w1, s1.y, a1y);
        a2x = fmaf(w2, s2.x, a2x);  a2y = fmaf(w2, s2.y, a2y);
        a3x = fmaf(w3, s3.x, a3x);  a3y = fmaf(w3, s3.y, a3y);
    }
    for (int j = nq * 4; j < npair; ++j) {
        int4 p = ep4[j];
        int   c = hi ? p.z : p.x;  float w = __int_as_float(hi ? p.w : p.y);
        float2 s = __half22float2(src2[((size_t)c << 5) + li]);
        a0x = fmaf(w, s.x, a0x);  a0y = fmaf(w, s.y, a0y);
    }
    float accx = (a0x + a1x) + (a2x + a3x);
    float accy = (a0y + a1y) + (a2y + a3y);
    accx += __shfl_xor(accx, 32, 64);   // combine the two halves
    accy += __shfl_xor(accy, 32, 64);
    float2 sf = __half22float2(src2[((size_t)r << 5) + li]);
    float2 bb = ((const float2*)b)[li];
    float vx = dr * (accx + sf.x) + bb.x;
    float vy = dr * (accy + sf.y) + bb.y;
    if (!hi) {
        float2 o;
        o.x = vx > 0.0f ? vx : 0.0f;
        o.y = vy > 0.0f ? vy : 0.0f;
        ((float2*)out)[((size_t)r << 5) + li] = o;
    }
}

// Layer-2 aggregation fused with mean-pool (h2 never materialized).
__global__ __launch_bounds__(256) void k_aggB(const __half* __restrict__ src,
                                              const int* __restrict__ meta,
                                              const float* __restrict__ dinv,
                                              const int2* __restrict__ adj,
                                              const float* __restrict__ b,
                                              float* __restrict__ pool, int n) {
    __shared__ float part[4][64];
    int wv = threadIdx.x >> 6, lane = threadIdx.x & 63;
    int li = lane & 31;
    bool hi = lane >= 32;
    const __half2* src2 = (const __half2*)src;
    float px = 0.0f, py = 0.0f;
    for (int r = blockIdx.x * 4 + wv; r < n; r += gridDim.x * 4) {
        int m = meta[r];
        int len = m & 255;
        float dr = dinv[r];
        const int4* ep4 = (const int4*)(adj + (m >> 8));
        float a0x=0,a0y=0,a1x=0,a1y=0,a2x=0,a2y=0,a3x=0,a3y=0;
        int npair = (len + 1) >> 1;
        int nq = npair >> 2;
        for (int t = 0; t < nq; ++t) {
            int4 p0 = ep4[4 * t + 0];
            int4 p1 = ep4[4 * t + 1];
            int4 p2 = ep4[4 * t + 2];
            int4 p3 = ep4[4 * t + 3];
            int   c0 = hi ? p0.z : p0.x;  float w0 = __int_as_float(hi ? p0.w : p0.y);
            int   c1 = hi ? p1.z : p1.x;  float w1 = __int_as_float(hi ? p1.w : p1.y);
            int   c2 = hi ? p2.z : p2.x;  float w2 = __int_as_float(hi ? p2.w : p2.y);
            int   c3 = hi ? p3.z : p3.x;  float w3 = __int_as_float(hi ? p3.w : p3.y);
            float2 s0 = __half22float2(src2[((size_t)c0 << 5) + li]);
            float2 s1 = __half22float2(src2[((size_t)c1 << 5) + li]);
            float2 s2 = __half22float2(src2[((size_t)c2 << 5) + li]);
            float2 s3 = __half22float2(src2[((size_t)c3 << 5) + li]);
            a0x = fmaf(w0, s0.x, a0x);  a0y = fmaf(w0, s0.y, a0y);
            a1x = fmaf(w1, s1.x, a1x);  a1y = fmaf(w1, s1.y, a1y);
            a2x = fmaf(w2, s2.x, a2x);  a2y = fmaf(w2, s2.y, a2y);
            a3x = fmaf(w3, s3.x, a3x);  a3y = fmaf(w3, s3.y, a3y);
        }
        for (int j = nq * 4; j < npair; ++j) {
            int4 p = ep4[j];
            int   c = hi ? p.z : p.x;  float w = __int_as_float(hi ? p.w : p.y);
            float2 s = __half22float2(src2[((size_t)c << 5) + li]);
            a0x = fmaf(w, s.x, a0x);  a0y = fmaf(w, s.y, a0y);
        }
        float accx = (a0x + a1x) + (a2x + a3x);
        float accy = (a0y + a1y) + (a2y + a3y);
        accx += __shfl_xor(accx, 32, 64);
        accy += __shfl_xor(accy, 32, 64);
        float2 sf = __half22float2(src2[((size_t)r << 5) + li]);
        float2 bb = ((const float2*)b)[li];
        float vx = dr * (accx + sf.x) + bb.x;
        float vy = dr * (accy + sf.y) + bb.y;
        px += vx > 0.0f ? vx : 0.0f;    // both halves hold identical v;
        py += vy > 0.0f ? vy : 0.0f;    // only half0's px/py get stored
    }
    if (!hi) { part[wv][2 * li] = px; part[wv][2 * li + 1] = py; }
    __syncthreads();
    if (wv == 0) {
        float s = part[0][lane] + part[1][lane] + part[2][lane] + part[3][lane];
        atomicAdd(&pool[lane], s);
    }
}

// z = [pool/N, h_other]; out = relu(z @ Wc1 + bc1) @ Wc2 + bc2
__global__ __launch_bounds__(128) void k_head(const float* __restrict__ pool,
                                              const float* __restrict__ h_other,
                                              const float* __restrict__ Wc1,
                                              const float* __restrict__ bc1,
                                              const float* __restrict__ Wc2,
                                              const float* __restrict__ bc2,
                                              float* __restrict__ out, float invN) {
    __shared__ float z[128];
    __shared__ float hid[64];
    int t = threadIdx.x;
    z[t] = (t < 64) ? pool[t] * invN : h_other[t - 64];
    __syncthreads();
    if (t < 64) {
        float acc = bc1[t];
#pragma unroll
        for (int k = 0; k < 128; ++k) acc += z[k] * Wc1[k * 64 + t];
        hid[t] = acc > 0.0f ? acc : 0.0f;
    }
    __syncthreads();
    if (t < 3) {
        float acc = bc2[t];
#pragma unroll
        for (int j = 0; j < 64; ++j) acc += hid[j] * Wc2[j * 3 + t];
        out[t] = acc;
    }
}

extern "C" void kernel_launch(void* const* d_in, const int* in_sizes, int n_in,
                              void* d_out, int out_size, void* d_ws, size_t ws_size,
                              hipStream_t stream) {
    const float* x       = (const float*)d_in[0];
    const int*   ei      = (const int*)d_in[1];
    const float* attr    = (const float*)d_in[2];
    const float* W1      = (const float*)d_in[4];
    const float* b1      = (const float*)d_in[5];
    const float* W2      = (const float*)d_in[6];
    const float* b2      = (const float*)d_in[7];
    const float* Wc1     = (const float*)d_in[8];
    const float* bc1     = (const float*)d_in[9];
    const float* Wc2     = (const float*)d_in[10];
    const float* bc2     = (const float*)d_in[11];
    const float* h_other = (const float*)d_in[12];
    float* out = (float*)d_out;

    const int N = in_sizes[3];
    const int E = in_sizes[2];
    const size_t NH = (size_t)N * 64;
    const int P = (N + PRWS - 1) >> PSHIFT;   // partitions

    // workspace (float units):
    //  buf0[NH(half-used, fp16)] | buf1[NH] | dinv[N] | pool[64] | meta[N int]
    //  | pfill[P*PFS int] | pad-to-16B | region[P*PCAP u64] | adj[P*PCAP int2]
    float* ws0  = (float*)d_ws;
    __half* buf0 = (__half*)ws0;
    float* buf1 = ws0 + NH;
    float* dinv = buf1 + NH;
    float* pool = dinv + N;
    int*   meta = (int*)(pool + 64);
    int*   pfill = meta + N;
    size_t ofs = (size_t)(2 * NH) + N + 64 + N + (size_t)P * PFS;
    ofs = (ofs + 3) & ~(size_t)3;             // 16B align (for int4 adj reads)
    unsigned long long* region = (unsigned long long*)(ws0 + ofs);
    int2* adj = (int2*)(region + (size_t)P * PCAP);

    const int* rows = ei;
    const int* cols = ei + E;

    hipMemsetAsync(pool, 0, 64 * sizeof(float), stream);
    hipMemsetAsync(pfill, 0, (size_t)P * PFS * sizeof(int), stream);

    // --- adjacency build ---
    k_part<<<(E + 4095) / 4096, 1024, 0, stream>>>(rows, cols, attr, pfill, region, E);
    k_build<<<P, 1024, 0, stream>>>(region, pfill, adj, dinv, meta, N);

    // --- layer 1 (GEMM epilogue scales row r by dinv[r]) ---
    k_gemm64<<<(N + 15) / 16, 256, 0, stream>>>(x, W1, dinv, buf0, N);
    k_aggA<<<(N + 3) / 4, 256, 0, stream>>>(buf0, meta, dinv, adj, b1, buf1, N);

    // --- layer 2 (agg fused with mean-pool) ---
    k_gemm64<<<(N + 15) / 16, 256, 0, stream>>>(buf1, W2, dinv, buf0, N);
    k_aggB<<<2048, 256, 0, stream>>>(buf0, meta, dinv, adj, b2, pool, N);

    // --- head ---
    k_head<<<1, 128, 0, stream>>>(pool, h_other, Wc1, bc1, Wc2, bc2, out,
                                  1.0f / (float)N);
}

// Round 9
// 304.911 us; speedup vs baseline: 3.4129x; 1.0061x over previous
//
#include <hip/hip_runtime.h>
#include <hip/hip_bf16.h>
#include <hip/hip_fp16.h>

// ---------------------------------------------------------------------------
// GCN pipeline. R8 post-mortem: agg floor tracks the number of 64B lines
// touched by src gathers (bytes/2, reqs/2, instrs/2 each moved time <=15%;
// lines/edge stayed 2). R9: src stored as OCP fp8 e4m3, 64 features = 64B
// = ONE line per edge row. GEMM epilogue stores 16*dinv[c]*(XW)[c] as fp8
// (v_cvt_pk_fp8_f32); agg decodes pairs with v_cvt_pk_f32_fp8 and folds
// dr/16 into the row epilogue. Wave = 2 x 32-lane halves, 2 edges per
// int4 metadata load, x8 edges in flight (R8 structure kept).
// ---------------------------------------------------------------------------

#define PSHIFT 9
#define PRWS   512           // rows per partition
#define PCAP   10240         // slots per partition (8192 mean + pads + slack)
#define PFS    16            // pfill stride (ints) = one 64B line per counter
#define VT     4             // edges per thread in k_part

typedef float vf2 __attribute__((ext_vector_type(2)));

// Pass 1: partition edges. LDS ranks; one global atomic per (block,part).
__global__ __launch_bounds__(1024) void k_part(const int* __restrict__ rows,
                                               const int* __restrict__ cols,
                                               const float* __restrict__ attr,
                                               int* __restrict__ pfill,
                                               unsigned long long* __restrict__ region,
                                               int E) {
    __shared__ int cntS[256];
    __shared__ int baseS[256];
    int t = threadIdx.x;
    if (t < 256) cntS[t] = 0;
    __syncthreads();
    int e0 = blockIdx.x * (1024 * VT);
    int pa[VT], ra[VT];
    unsigned long long rec[VT];
#pragma unroll
    for (int i = 0; i < VT; ++i) {
        int e = e0 + i * 1024 + t;
        if (e < E) {
            int r = rows[e];
            int p = r >> PSHIFT;
            pa[i]  = p;
            rec[i] = ((unsigned long long)__float_as_uint(attr[e]) << 32) |
                     ((unsigned)(r & (PRWS - 1)) << 17) | (unsigned)cols[e];
            ra[i]  = atomicAdd(&cntS[p], 1);            // LDS atomic
        } else pa[i] = -1;
    }
    __syncthreads();
    if (t < 256 && cntS[t] > 0)
        baseS[t] = atomicAdd(&pfill[t * PFS], cntS[t]); // one global atomic
    __syncthreads();
#pragma unroll
    for (int i = 0; i < VT; ++i) {
        if (pa[i] >= 0) {
            int pos = baseS[pa[i]] + ra[i];
            if (pos < PCAP)
                region[(size_t)pa[i] * PCAP + pos] = rec[i];
        }
    }
}

// Pass 2: one block per partition. Row starts even-aligned; odd rows get a
// ZEROED pad slot (col=0, w=0). Emits adj, dinv, meta=(start<<8)|cnt.
__global__ __launch_bounds__(1024) void k_build(unsigned long long* __restrict__ region,
                                                const int* __restrict__ pfill,
                                                int2* __restrict__ adj,
                                                float* __restrict__ dinv,
                                                int* __restrict__ meta, int N) {
    __shared__ int   cntS[PRWS];
    __shared__ int   c2S[PRWS];
    __shared__ float asum[PRWS];
    __shared__ int   scan[PRWS];
    __shared__ int   startS[PRWS];
    int p = blockIdx.x, t = threadIdx.x;
    int len = min(pfill[p * PFS], PCAP);
    if (t < PRWS) { cntS[t] = 0; c2S[t] = 0; asum[t] = 0.0f; }
    __syncthreads();
    const unsigned long long* base = region + (size_t)p * PCAP;
    for (int j = t; j < len; j += 1024) {
        unsigned long long v = base[j];
        int rl = (int)((v >> 17) & (PRWS - 1));
        atomicAdd(&cntS[rl], 1);
        atomicAdd(&asum[rl], __uint_as_float((unsigned)(v >> 32)));
    }
    __syncthreads();
    if (t < PRWS) scan[t] = (cntS[t] + 1) & ~1;   // even-padded counts
    __syncthreads();
    for (int off = 1; off < PRWS; off <<= 1) {
        int v = 0;
        if (t < PRWS && t >= off) v = scan[t - off];
        __syncthreads();
        if (t < PRWS) scan[t] += v;
        __syncthreads();
    }
    int r0 = p * PRWS;
    if (t < PRWS) {
        int pad = (cntS[t] + 1) & ~1;
        int start = p * PCAP + (scan[t] - pad);   // even offset
        startS[t] = start;
        int r = r0 + t;
        if (r < N) {
            meta[r] = (start << 8) | min(cntS[t], 255);
            dinv[r] = rsqrtf(1.0f + asum[t]);
        }
        if (cntS[t] & 1) adj[start + cntS[t]] = make_int2(0, 0);  // zero pad
    }
    __syncthreads();
    for (int j = t; j < len; j += 1024) {
        unsigned long long v = base[j];
        int rl   = (int)((v >> 17) & (PRWS - 1));
        int rank = atomicAdd(&c2S[rl], 1);
        adj[startS[rl] + rank] = make_int2((int)(v & 0x1FFFF), (int)(v >> 32));
    }
}

// out[n x 64] (fp8 e4m3) = 16*dscale[r] * (in[n x 64] @ W[64 x 64]);
// 16 rows/block, thread = 1 row x 4 cols; packs 4 fp8 into one uint store.
__global__ __launch_bounds__(256) void k_gemm64(const float* __restrict__ in,
                                                const float* __restrict__ W,
                                                const float* __restrict__ dscale,
                                                unsigned* __restrict__ out, int n) {
    __shared__ float4 ws4[64][16];
    __shared__ float xs[16][64];
    int t = threadIdx.x;
    const float4* W4 = (const float4*)W;
    for (int i = t; i < 1024; i += 256) ((float4*)ws4)[i] = W4[i];
    int r0 = blockIdx.x * 16;
    int rr = t >> 4, c4 = t & 15;
    if (r0 + rr < n)
        ((float4*)xs)[t] = ((const float4*)in)[(size_t)(r0 + rr) * 16 + c4];
    __syncthreads();
    if (r0 + rr < n) {
        float4 acc = {0.f, 0.f, 0.f, 0.f};
#pragma unroll
        for (int k = 0; k < 64; ++k) {
            float xv = xs[rr][k];
            float4 wv = ws4[k][c4];
            acc.x = fmaf(xv, wv.x, acc.x);
            acc.y = fmaf(xv, wv.y, acc.y);
            acc.z = fmaf(xv, wv.z, acc.z);
            acc.w = fmaf(xv, wv.w, acc.w);
        }
        float ds = dscale[r0 + rr] * 16.0f;   // 16x keeps e4m3 in normal range
        int pk = __builtin_amdgcn_cvt_pk_fp8_f32(acc.x * ds, acc.y * ds, 0, false);
        pk = __builtin_amdgcn_cvt_pk_fp8_f32(acc.z * ds, acc.w * ds, pk, true);
        out[(size_t)(r0 + rr) * 16 + c4] = (unsigned)pk;
    }
}

// Layer-1 aggregation: wave = 2 x 32-lane halves; each half gathers a
// different edge's 64B fp8 row (lane li: features 2li,2li+1 as one ushort,
// decoded with v_cvt_pk_f32_fp8). Cross-half combine via shfl_xor(32).
__global__ __launch_bounds__(256) void k_aggA(const unsigned short* __restrict__ src,
                                              const int* __restrict__ meta,
                                              const float* __restrict__ dinv,
                                              const int2* __restrict__ adj,
                                              const float* __restrict__ b,
                                              float* __restrict__ out, int n) {
    int r = blockIdx.x * 4 + (threadIdx.x >> 6);
    int lane = threadIdx.x & 63;
    if (r >= n) return;
    int li = lane & 31;
    bool hi = lane >= 32;
    int m = meta[r];
    int len = m & 255;
    float dr = dinv[r] * 0.0625f;           // fold 1/16 fp8 scale back out
    const int4* ep4 = (const int4*)(adj + (m >> 8));
    float a0x=0,a0y=0,a1x=0,a1y=0,a2x=0,a2y=0,a3x=0,a3y=0;
    int npair = (len + 1) >> 1;             // pad slot is zeroed -> safe
    int nq = npair >> 2;
    for (int t = 0; t < nq; ++t) {
        int4 p0 = ep4[4 * t + 0];
        int4 p1 = ep4[4 * t + 1];
        int4 p2 = ep4[4 * t + 2];
        int4 p3 = ep4[4 * t + 3];
        int   c0 = hi ? p0.z : p0.x;  float w0 = __int_as_float(hi ? p0.w : p0.y);
        int   c1 = hi ? p1.z : p1.x;  float w1 = __int_as_float(hi ? p1.w : p1.y);
        int   c2 = hi ? p2.z : p2.x;  float w2 = __int_as_float(hi ? p2.w : p2.y);
        int   c3 = hi ? p3.z : p3.x;  float w3 = __int_as_float(hi ? p3.w : p3.y);
        vf2 s0 = __builtin_amdgcn_cvt_pk_f32_fp8((int)src[((size_t)c0 << 5) + li], false);
        vf2 s1 = __builtin_amdgcn_cvt_pk_f32_fp8((int)src[((size_t)c1 << 5) + li], false);
        vf2 s2 = __builtin_amdgcn_cvt_pk_f32_fp8((int)src[((size_t)c2 << 5) + li], false);
        vf2 s3 = __builtin_amdgcn_cvt_pk_f32_fp8((int)src[((size_t)c3 << 5) + li], false);
        a0x = fmaf(w0, s0.x, a0x);  a0y = fmaf(w0, s0.y, a0y);
        a1x = fmaf(w1, s1.x, a1x);  a1y = fmaf(w1, s1.y, a1y);
        a2x = fmaf(w2, s2.x, a2x);  a2y = fmaf(w2, s2.y, a2y);
        a3x = fmaf(w3, s3.x, a3x);  a3y = fmaf(w3, s3.y, a3y);
    }
    for (int j = nq * 4; j < npair; ++j) {
        int4 p = ep4[j];
        int   c = hi ? p.z : p.x;  float w = __int_as_float(hi ? p.w : p.y);
        vf2 s = __builtin_amdgcn_cvt_pk_f32_fp8((int)src[((size_t)c << 5) + li], false);
        a0x = fmaf(w, s.x, a0x);  a0y = fmaf(w, s.y, a0y);
    }
    float accx = (a0x + a1x) + (a2x + a3x);
    float accy = (a0y + a1y) + (a2y + a3y);
    accx += __shfl_xor(accx, 32, 64);       // combine the two halves
    accy += __shfl_xor(accy, 32, 64);
    vf2 sf = __builtin_amdgcn_cvt_pk_f32_fp8((int)src[((size_t)r << 5) + li], false);
    float2 bb = ((const float2*)b)[li];
    float vx = dr * (accx + sf.x) + bb.x;
    float vy = dr * (accy + sf.y) + bb.y;
    if (!hi) {
        float2 o;
        o.x = vx > 0.0f ? vx : 0.0f;
        o.y = vy > 0.0f ? vy : 0.0f;
        ((float2*)out)[((size_t)r << 5) + li] = o;
    }
}

// Layer-2 aggregation fused with mean-pool (h2 never materialized).
__global__ __launch_bounds__(256) void k_aggB(const unsigned short* __restrict__ src,
                                              const int* __restrict__ meta,
                                              const float* __restrict__ dinv,
                                              const int2* __restrict__ adj,
                                              const float* __restrict__ b,
                                              float* __restrict__ pool, int n) {
    __shared__ float part[4][64];
    int wv = threadIdx.x >> 6, lane = threadIdx.x & 63;
    int li = lane & 31;
    bool hi = lane >= 32;
    float px = 0.0f, py = 0.0f;
    for (int r = blockIdx.x * 4 + wv; r < n; r += gridDim.x * 4) {
        int m = meta[r];
        int len = m & 255;
        float dr = dinv[r] * 0.0625f;
        const int4* ep4 = (const int4*)(adj + (m >> 8));
        float a0x=0,a0y=0,a1x=0,a1y=0,a2x=0,a2y=0,a3x=0,a3y=0;
        int npair = (len + 1) >> 1;
        int nq = npair >> 2;
        for (int t = 0; t < nq; ++t) {
            int4 p0 = ep4[4 * t + 0];
            int4 p1 = ep4[4 * t + 1];
            int4 p2 = ep4[4 * t + 2];
            int4 p3 = ep4[4 * t + 3];
            int   c0 = hi ? p0.z : p0.x;  float w0 = __int_as_float(hi ? p0.w : p0.y);
            int   c1 = hi ? p1.z : p1.x;  float w1 = __int_as_float(hi ? p1.w : p1.y);
            int   c2 = hi ? p2.z : p2.x;  float w2 = __int_as_float(hi ? p2.w : p2.y);
            int   c3 = hi ? p3.z : p3.x;  float w3 = __int_as_float(hi ? p3.w : p3.y);
            vf2 s0 = __builtin_amdgcn_cvt_pk_f32_fp8((int)src[((size_t)c0 << 5) + li], false);
            vf2 s1 = __builtin_amdgcn_cvt_pk_f32_fp8((int)src[((size_t)c1 << 5) + li], false);
            vf2 s2 = __builtin_amdgcn_cvt_pk_f32_fp8((int)src[((size_t)c2 << 5) + li], false);
            vf2 s3 = __builtin_amdgcn_cvt_pk_f32_fp8((int)src[((size_t)c3 << 5) + li], false);
            a0x = fmaf(w0, s0.x, a0x);  a0y = fmaf(w0, s0.y, a0y);
            a1x = fmaf(w1, s1.x, a1x);  a1y = fmaf(w1, s1.y, a1y);
            a2x = fmaf(w2, s2.x, a2x);  a2y = fmaf(w2, s2.y, a2y);
            a3x = fmaf(w3, s3.x, a3x);  a3y = fmaf(w3, s3.y, a3y);
        }
        for (int j = nq * 4; j < npair; ++j) {
            int4 p = ep4[j];
            int   c = hi ? p.z : p.x;  float w = __int_as_float(hi ? p.w : p.y);
            vf2 s = __builtin_amdgcn_cvt_pk_f32_fp8((int)src[((size_t)c << 5) + li], false);
            a0x = fmaf(w, s.x, a0x);  a0y = fmaf(w, s.y, a0y);
        }
        float accx = (a0x + a1x) + (a2x + a3x);
        float accy = (a0y + a1y) + (a2y + a3y);
        accx += __shfl_xor(accx, 32, 64);
        accy += __shfl_xor(accy, 32, 64);
        vf2 sf = __builtin_amdgcn_cvt_pk_f32_fp8((int)src[((size_t)r << 5) + li], false);
        float2 bb = ((const float2*)b)[li];
        float vx = dr * (accx + sf.x) + bb.x;
        float vy = dr * (accy + sf.y) + bb.y;
        px += vx > 0.0f ? vx : 0.0f;    // both halves identical; half0 stores
        py += vy > 0.0f ? vy : 0.0f;
    }
    if (!hi) { part[wv][2 * li] = px; part[wv][2 * li + 1] = py; }
    __syncthreads();
    if (wv == 0) {
        float s = part[0][lane] + part[1][lane] + part[2][lane] + part[3][lane];
        atomicAdd(&pool[lane], s);
    }
}

// z = [pool/N, h_other]; out = relu(z @ Wc1 + bc1) @ Wc2 + bc2
__global__ __launch_bounds__(128) void k_head(const float* __restrict__ pool,
                                              const float* __restrict__ h_other,
                                              const float* __restrict__ Wc1,
                                              const float* __restrict__ bc1,
                                              const float* __restrict__ Wc2,
                                              const float* __restrict__ bc2,
                                              float* __restrict__ out, float invN) {
    __shared__ float z[128];
    __shared__ float hid[64];
    int t = threadIdx.x;
    z[t] = (t < 64) ? pool[t] * invN : h_other[t - 64];
    __syncthreads();
    if (t < 64) {
        float acc = bc1[t];
#pragma unroll
        for (int k = 0; k < 128; ++k) acc += z[k] * Wc1[k * 64 + t];
        hid[t] = acc > 0.0f ? acc : 0.0f;
    }
    __syncthreads();
    if (t < 3) {
        float acc = bc2[t];
#pragma unroll
        for (int j = 0; j < 64; ++j) acc += hid[j] * Wc2[j * 3 + t];
        out[t] = acc;
    }
}

extern "C" void kernel_launch(void* const* d_in, const int* in_sizes, int n_in,
                              void* d_out, int out_size, void* d_ws, size_t ws_size,
                              hipStream_t stream) {
    const float* x       = (const float*)d_in[0];
    const int*   ei      = (const int*)d_in[1];
    const float* attr    = (const float*)d_in[2];
    const float* W1      = (const float*)d_in[4];
    const float* b1      = (const float*)d_in[5];
    const float* W2      = (const float*)d_in[6];
    const float* b2      = (const float*)d_in[7];
    const float* Wc1     = (const float*)d_in[8];
    const float* bc1     = (const float*)d_in[9];
    const float* Wc2     = (const float*)d_in[10];
    const float* bc2     = (const float*)d_in[11];
    const float* h_other = (const float*)d_in[12];
    float* out = (float*)d_out;

    const int N = in_sizes[3];
    const int E = in_sizes[2];
    const size_t NH = (size_t)N * 64;
    const int P = (N + PRWS - 1) >> PSHIFT;   // partitions

    // workspace (float units):
    //  buf0[NH floats reserved; used as N*64 fp8 bytes] | buf1[NH] | dinv[N]
    //  | pool[64] | meta[N int] | pfill[P*PFS int] | pad-to-16B
    //  | region[P*PCAP u64] | adj[P*PCAP int2]
    float* ws0  = (float*)d_ws;
    unsigned* buf0 = (unsigned*)ws0;          // fp8 rows, 16 uints per row
    float* buf1 = ws0 + NH;
    float* dinv = buf1 + NH;
    float* pool = dinv + N;
    int*   meta = (int*)(pool + 64);
    int*   pfill = meta + N;
    size_t ofs = (size_t)(2 * NH) + N + 64 + N + (size_t)P * PFS;
    ofs = (ofs + 3) & ~(size_t)3;             // 16B align (for int4 adj reads)
    unsigned long long* region = (unsigned long long*)(ws0 + ofs);
    int2* adj = (int2*)(region + (size_t)P * PCAP);

    const int* rows = ei;
    const int* cols = ei + E;

    hipMemsetAsync(pool, 0, 64 * sizeof(float), stream);
    hipMemsetAsync(pfill, 0, (size_t)P * PFS * sizeof(int), stream);

    // --- adjacency build ---
    k_part<<<(E + 4095) / 4096, 1024, 0, stream>>>(rows, cols, attr, pfill, region, E);
    k_build<<<P, 1024, 0, stream>>>(region, pfill, adj, dinv, meta, N);

    // --- layer 1 (GEMM epilogue: fp8 of 16*dinv[r]*row) ---
    k_gemm64<<<(N + 15) / 16, 256, 0, stream>>>(x, W1, dinv, buf0, N);
    k_aggA<<<(N + 3) / 4, 256, 0, stream>>>((const unsigned short*)buf0, meta, dinv,
                                            adj, b1, buf1, N);

    // --- layer 2 (agg fused with mean-pool) ---
    k_gemm64<<<(N + 15) / 16, 256, 0, stream>>>(buf1, W2, dinv, buf0, N);
    k_aggB<<<2048, 256, 0, stream>>>((const unsigned short*)buf0, meta, dinv,
                                     adj, b2, pool, N);

    // --- head ---
    k_head<<<1, 128, 0, stream>>>(pool, h_other, Wc1, bc1, Wc2, bc2, out,
                                  1.0f / (float)N);
}